// Round 4
// baseline (319.335 us; speedup 1.0000x reference)
//
#include <hip/hip_runtime.h>
#include <math.h>

#define D_MODEL 1024
#define N_SEQ   4096
#define N_HEADS 16
#define DHEAD   64
#define QKV_COLS 3072   // 3 * 1024

typedef short bf16x8 __attribute__((ext_vector_type(8)));
typedef short bf16x4 __attribute__((ext_vector_type(4)));
typedef float f32x4  __attribute__((ext_vector_type(4)));

#define MFMA32(a, b, c) __builtin_amdgcn_mfma_f32_16x16x32_bf16(a, b, c, 0, 0, 0)
// v_mfma_f32_16x16x16_bf16 (2/2/4 regs) — gfx90a-lineage builtin, valid on gfx950.
#define MFMA16(a, b, c) __builtin_amdgcn_mfma_f32_16x16x16bf16_1k(a, b, c, 0, 0, 0)

static __device__ __forceinline__ unsigned short f2bf(float f) {
    union { float f; unsigned u; } v; v.f = f;
    unsigned r = (v.u + 0x7fffu + ((v.u >> 16) & 1u)) >> 16;
    return (unsigned short)r;
}

// pack 4 floats -> 4 bf16 by truncation (1 v_perm_b32 per pair)
static __device__ __forceinline__ bf16x4 pack_bf16x4(float a, float b, float c, float d) {
    union { float f; unsigned u; } x0, x1, x2, x3;
    x0.f = a; x1.f = b; x2.f = c; x3.f = d;
    union { unsigned u[2]; bf16x4 v; } r;
    r.u[0] = __builtin_amdgcn_perm(x1.u, x0.u, 0x07060302u);
    r.u[1] = __builtin_amdgcn_perm(x3.u, x2.u, 0x07060302u);
    return r.v;
}

typedef __attribute__((address_space(1))) const void* gas_t;
typedef __attribute__((address_space(3))) void* las_t;
static __device__ __forceinline__ void load_lds16(const unsigned short* g, unsigned short* l) {
    __builtin_amdgcn_global_load_lds((gas_t)g, (las_t)l, 16, 0, 0);
}

// slot->u permutation for flash_mfma: blockIdx = 16*s + h. With round-robin
// block->XCD dispatch, CU-class = s%16 (5 slots per class: s = c+16k). Job
// weights (ktiles): 48 jobs @16 + four sets {2,4,..,16}. This table gives
// every class exactly 3x16 + an 18-sum pair = 66 tiles -> zero imbalance,
// while h stays in the low 4 bits (head->XCD L2 affinity preserved).
__constant__ unsigned char U_TAB[80] = {
    // k=0 (heavy)
    71,65,59,54,49,45,40,36,31,27,23,19,15,11,7,3,
    // k=1 (heavy)
    69,63,57,52,48,43,39,34,30,26,22,18,14,10,6,2,
    // k=2 (heavy)
    67,61,55,51,46,42,37,33,29,25,21,17,13,9,5,1,
    // k=3 (pair a: weights 2,4,6,8 / 2,4,6,8 / 2,4,6,8 / 2,4,6,8)
    70,68,66,64,53,50,47,44,28,24,20,16,79,78,77,76,
    // k=4 (pair b: weights 16,14,12,10 / 16,14,12,10 / 16,14,12,10 / 16,14,12,10)
    56,58,60,62,32,35,38,41,0,4,8,12,72,73,74,75
};

// ---------------- LayerNorm: one block per row, bf16 out ----------------
__global__ __launch_bounds__(256) void ln_kernel(const float* __restrict__ x,
                                                 const float* __restrict__ g,
                                                 const float* __restrict__ b,
                                                 unsigned short* __restrict__ h) {
    int row = blockIdx.x;
    int t = threadIdx.x;
    float4 v = ((const float4*)(x + (size_t)row * D_MODEL))[t];
    float s  = v.x + v.y + v.z + v.w;
    float ss = v.x*v.x + v.y*v.y + v.z*v.z + v.w*v.w;
    for (int off = 32; off; off >>= 1) {
        s  += __shfl_down(s, off);
        ss += __shfl_down(ss, off);
    }
    __shared__ float sm[4], ssm[4];
    __shared__ float mu_s, rs_s;
    int wave = t >> 6, lane = t & 63;
    if (lane == 0) { sm[wave] = s; ssm[wave] = ss; }
    __syncthreads();
    if (t == 0) {
        float S = 0.f, SS = 0.f;
        for (int w = 0; w < 4; w++) { S += sm[w]; SS += ssm[w]; }
        float mu = S / D_MODEL;
        float var = SS / D_MODEL - mu * mu;
        mu_s = mu;
        rs_s = rsqrtf(var + 1e-5f);
    }
    __syncthreads();
    float mu = mu_s, rs = rs_s;
    float4 gv = ((const float4*)g)[t];
    float4 bv = ((const float4*)b)[t];
    ushort4 o;
    o.x = f2bf((v.x - mu) * rs * gv.x + bv.x);
    o.y = f2bf((v.y - mu) * rs * gv.y + bv.y);
    o.z = f2bf((v.z - mu) * rs * gv.z + bv.z);
    o.w = f2bf((v.w - mu) * rs * gv.w + bv.w);
    *(ushort4*)(h + (size_t)row * D_MODEL + t * 4) = o;
}

// ------------- transpose + fp32->bf16: W[K][N] -> Wt[N][K] -------------
__global__ __launch_bounds__(256) void transpose_cvt(const float* __restrict__ W,
                                                     unsigned short* __restrict__ Wt,
                                                     int K, int N) {
    __shared__ float tile[64][65];
    int k0 = blockIdx.x * 64, n0 = blockIdx.y * 64;
    int t = threadIdx.x;
#pragma unroll
    for (int p = 0; p < 16; p++) {
        int idx = p * 256 + t;
        int r = idx >> 6, c = idx & 63;
        tile[r][c] = W[(size_t)(k0 + r) * N + n0 + c];
    }
    __syncthreads();
#pragma unroll
    for (int p = 0; p < 16; p++) {
        int idx = p * 256 + t;
        int r2 = idx >> 6, c2 = idx & 63;
        Wt[(size_t)(n0 + r2) * K + k0 + c2] = f2bf(tile[c2][r2]);
    }
}

// ---- m97-style MFMA bf16 GEMM: C[M,N] = A[M,K] * Bt[N,K]^T, fp32 out ----
__global__ __launch_bounds__(256) void gemm_bt128(const unsigned short* __restrict__ A,
                                                  const unsigned short* __restrict__ Bt,
                                                  float* __restrict__ C,
                                                  int M, int N, int K) {
    __shared__ unsigned short As[128 * 32];
    __shared__ unsigned short Bs[128 * 32];
    int t = threadIdx.x;
    int w = t >> 6, lane = t & 63;
    int l16 = lane & 15, quad = lane >> 4;
    int wr = w >> 1, wc = w & 1;
    int m0 = blockIdx.x * 128, n0 = blockIdx.y * 128;
    int srow = lane >> 2, scol = (lane & 3) * 8;
    int c0 = w * 2, c1 = c0 + 1;

    f32x4 acc[4][4] = {};

    for (int k0 = 0; k0 < K; k0 += 32) {
        __syncthreads();
        load_lds16(A  + (size_t)(m0 + c0 * 16 + srow) * K + k0 + scol, &As[c0 * 512 + lane * 8]);
        load_lds16(A  + (size_t)(m0 + c1 * 16 + srow) * K + k0 + scol, &As[c1 * 512 + lane * 8]);
        load_lds16(Bt + (size_t)(n0 + c0 * 16 + srow) * K + k0 + scol, &Bs[c0 * 512 + lane * 8]);
        load_lds16(Bt + (size_t)(n0 + c1 * 16 + srow) * K + k0 + scol, &Bs[c1 * 512 + lane * 8]);
        __syncthreads();
        bf16x8 a[4], b[4];
#pragma unroll
        for (int mt = 0; mt < 4; mt++)
            a[mt] = *(const bf16x8*)&As[(wr * 64 + mt * 16 + l16) * 32 + quad * 8];
#pragma unroll
        for (int nt = 0; nt < 4; nt++)
            b[nt] = *(const bf16x8*)&Bs[(wc * 64 + nt * 16 + l16) * 32 + quad * 8];
#pragma unroll
        for (int mt = 0; mt < 4; mt++)
#pragma unroll
            for (int nt = 0; nt < 4; nt++)
                acc[mt][nt] = MFMA32(a[mt], b[nt], acc[mt][nt]);
    }
#pragma unroll
    for (int mt = 0; mt < 4; mt++)
#pragma unroll
        for (int nt = 0; nt < 4; nt++)
#pragma unroll
            for (int r = 0; r < 4; r++)
                C[(size_t)(m0 + wr * 64 + mt * 16 + quad * 4 + r) * N + n0 + wc * 64 + nt * 16 + l16] =
                    acc[mt][nt][r];
}

// --------- rope + caches. grid (64 ntiles, 16 heads), 256 thr ----------
__global__ __launch_bounds__(256) void rope_cache_kernel(const float* __restrict__ qkv,
                                                         float* __restrict__ out_k,
                                                         float* __restrict__ out_v,
                                                         unsigned short* __restrict__ q_bf,
                                                         unsigned short* __restrict__ k_bf,
                                                         unsigned short* __restrict__ vt_bf) {
    __shared__ unsigned short Vt[64 * 72];
    int nt = blockIdx.x, h = blockIdx.y;
    int n0 = nt * 64;
    int t = threadIdx.x;
    int row = t >> 2;
    int n = n0 + row;
    const float* src = qkv + (size_t)n * QKV_COLS + h * 64;
    size_t nd_base = ((size_t)h * N_SEQ + n) * 64;
#pragma unroll
    for (int j = 0; j < 4; j++) {
        int c = (t & 3) * 4 + j * 16;
        float4 q4 = *(const float4*)(src + c);
        float4 k4 = *(const float4*)(src + 1024 + c);
        float4 v4 = *(const float4*)(src + 2048 + c);
        *(float4*)(out_k + nd_base + c) = k4;
        *(float4*)(out_v + nd_base + c) = v4;
        float i0 = (float)(c >> 1), i1 = i0 + 1.f;
        float if0 = powf(10000.0f, -i0 / 32.0f);
        float if1 = powf(10000.0f, -i1 / 32.0f);
        float s0, c0s, s1, c1s;
        sincosf((float)n * if0, &s0, &c0s);
        sincosf((float)n * if1, &s1, &c1s);
        ushort4 qo, ko;
        qo.x = f2bf(q4.x * c0s - q4.y * s0); qo.y = f2bf(q4.y * c0s + q4.x * s0);
        qo.z = f2bf(q4.z * c1s - q4.w * s1); qo.w = f2bf(q4.w * c1s + q4.z * s1);
        ko.x = f2bf(k4.x * c0s - k4.y * s0); ko.y = f2bf(k4.y * c0s + k4.x * s0);
        ko.z = f2bf(k4.z * c1s - k4.w * s1); ko.w = f2bf(k4.w * c1s + k4.z * s1);
        *(ushort4*)(q_bf + nd_base + c) = qo;
        *(ushort4*)(k_bf + nd_base + c) = ko;
        ushort4 vo;
        vo.x = f2bf(v4.x); vo.y = f2bf(v4.y); vo.z = f2bf(v4.z); vo.w = f2bf(v4.w);
        *(ushort4*)&Vt[row * 72 + c] = vo;
    }
    __syncthreads();
    int d = t >> 2;
    int nb = (t & 3) * 16;
    unsigned short tmp[16];
#pragma unroll
    for (int i = 0; i < 16; i++) tmp[i] = Vt[(nb + i) * 72 + d];
    unsigned short* dst = vt_bf + ((size_t)h * DHEAD + d) * N_SEQ + n0 + nb;
#pragma unroll
    for (int i = 0; i < 16; i++) dst[i] = tmp[i];
}

// ------------- MFMA flash attention (causal, S^T form, split-K) -------------
// STATIC 1280 blocks x 256 thr; job = (h = idx&15, u = U_TAB[idx>>4]).
// h in low 4 bits -> all of head h lands on XCD h%8 (round-robin dispatch),
// so each XCD's L2 holds just 2 heads' K/V (2 MB) -> minimal HBM fetch
// (the r3 dynamic queue broke this: FETCH 12.5->77 MB, net loss).
// U_TAB balances per-CU load exactly (66 ktiles per 5-slot class).
// LDS exactly 32 KiB -> 5 blocks/CU co-resident (160 KiB LDS fully used).
// u<72: partial chunk (Qt>=8, 16-ktile chunk), writes fp32 O^T partial + l.
// u>=72: Qt<8, full range, writes attn direct. 2-phase double-buffered LDS;
// l accumulated on the MFMA pipe via the ones-row trick.
__global__ __launch_bounds__(256, 5) void flash_mfma(const unsigned short* __restrict__ q_bf,
                                                     const unsigned short* __restrict__ k_bf,
                                                     const unsigned short* __restrict__ vt_bf,
                                                     unsigned short* __restrict__ attn_bf,
                                                     float* __restrict__ part_O,
                                                     float* __restrict__ part_l) {
    int idx = blockIdx.x;
    int h = idx & 15;
    int u = U_TAB[idx >> 4];
    int Qt, cc;
    bool partial = (u < 72);
    if (partial) {
        int r = 71 - u;
        if (r < 16)      { Qt = 8 + (r >> 1); cc = r & 1; }
        else if (r < 40) { int q3 = r - 16; int d3 = q3 / 3; Qt = 16 + d3; cc = q3 - 3 * d3; }
        else             { int q4 = r - 40; Qt = 24 + (q4 >> 2); cc = q4 & 3; }
    } else { Qt = 79 - u; cc = 0; }
    int kt0 = cc * 16;
    int kt_end = min(kt0 + 15, 2 * Qt + 1);

    int t = threadIdx.x;
    int w = t >> 6, lane = t & 63;
    int l16 = lane & 15, quad = lane >> 4;
    int sw = l16 & 7;

    __shared__ unsigned short Ks[2][4096];   // 2 x 8KB, double-buffered
    __shared__ unsigned short Vs[2][4096];   // total LDS exactly 32 KiB

    int qr0 = Qt * 128 + w * 32;
    const unsigned short* Kg = k_bf + (size_t)h * N_SEQ * DHEAD;
    const unsigned short* Vg = vt_bf + (size_t)h * DHEAD * N_SEQ;

    bf16x8 bq[2][2];
#pragma unroll
    for (int qg = 0; qg < 2; qg++) {
        const unsigned short* qp = q_bf + ((size_t)h * N_SEQ + qr0 + qg * 16 + l16) * 64 + quad * 8;
        bq[qg][0] = *(const bf16x8*)(qp);
        bq[qg][1] = *(const bf16x8*)(qp + 32);
    }
    f32x4 O[2][4] = {};
    f32x4 Ol[2] = {};                  // row-sum accumulator: l = sum_k P (ones-MFMA)
    int my_kmax = (qr0 + 31) >> 6;

    int srow = t >> 3;
    int scol = ((t & 7) ^ (srow & 7)) * 8;
    const float CEXP = 0.18033688011112042f;   // 0.125 * log2(e)

    // ---- loop-invariant LDS fragment offsets (hoisted; static-indexed) ----
    int koffA[4], koffB[4];
#pragma unroll
    for (int tt = 0; tt < 4; tt++) {
        int krow = tt * 16 + l16;
        koffA[tt] = krow * 64 + ((quad ^ sw) * 8);
        koffB[tt] = krow * 64 + (((quad + 4) ^ sw) * 8);
    }
    int voff[4][4];
#pragma unroll
    for (int tt = 0; tt < 4; tt++)
#pragma unroll
        for (int dt = 0; dt < 4; dt++)
            voff[tt][dt] = (dt * 16 + l16) * 64 +
                           (((2 * tt + (quad >> 1)) ^ sw) * 8) + (quad & 1) * 4;

    // ---- staging pointers (advance by constants each tile) ----
    const unsigned short* kg0 = Kg + (size_t)(kt0 * 64 + srow) * 64 + scol;
    const unsigned short* kg1 = kg0 + 2048;                 // +32 rows
    const unsigned short* vg0 = Vg + (size_t)srow * N_SEQ + kt0 * 64 + scol;
    const unsigned short* vg1 = vg0 + (size_t)32 * N_SEQ;   // +32 d-rows

    const bf16x4 ones4 = {(short)0x3F80, (short)0x3F80, (short)0x3F80, (short)0x3F80};

    // prologue: stage kt0 into buffer 0
    load_lds16(kg0, &Ks[0][t * 8]);
    load_lds16(kg1, &Ks[0][t * 8 + 2048]);
    load_lds16(vg0, &Vs[0][t * 8]);
    load_lds16(vg1, &Vs[0][t * 8 + 2048]);
    kg0 += 4096; kg1 += 4096; vg0 += 64; vg1 += 64;

    // one step: barrier (drains prev stage + prev reads), issue next stage,
    // compute current buffer. Compile-time buffer bases fold into offsets.
    auto step = [&](int kt, const unsigned short* KC, const unsigned short* VC,
                    unsigned short* KN, unsigned short* VN) {
        __syncthreads();
        if (kt < kt_end) {
            load_lds16(kg0, KN + t * 8);
            load_lds16(kg1, KN + t * 8 + 2048);
            load_lds16(vg0, VN + t * 8);
            load_lds16(vg1, VN + t * 8 + 2048);
            kg0 += 4096; kg1 += 4096; vg0 += 64; vg1 += 64;
        }
        if (kt > my_kmax) return;
        int k0 = kt << 6;

        bf16x4 pf[2][4];
#pragma unroll
        for (int tt = 0; tt < 4; tt++) {
            int kbase = k0 + tt * 16;
            bf16x4 pz = (bf16x4){0, 0, 0, 0};
            if (kbase >= qr0 + 32) { pf[0][tt] = pz; pf[1][tt] = pz; continue; }
            bf16x8 kf0 = *(const bf16x8*)&KC[koffA[tt]];
            bf16x8 kf1 = *(const bf16x8*)&KC[koffB[tt]];
#pragma unroll
            for (int qg = 0; qg < 2; qg++) {
                int qb = qr0 + qg * 16;
                if (kbase > qb) { pf[qg][tt] = pz; continue; }
                f32x4 s = (f32x4){0.f, 0.f, 0.f, 0.f};
                s = MFMA32(kf0, bq[qg][0], s);
                s = MFMA32(kf1, bq[qg][1], s);
                float p0 = exp2f(s[0] * CEXP);
                float p1 = exp2f(s[1] * CEXP);
                float p2 = exp2f(s[2] * CEXP);
                float p3 = exp2f(s[3] * CEXP);
                if (kbase == qb) {   // diagonal tile: mask key > q
                    if (quad * 4 + 0 > l16) p0 = 0.f;
                    if (quad * 4 + 1 > l16) p1 = 0.f;
                    if (quad * 4 + 2 > l16) p2 = 0.f;
                    if (quad * 4 + 3 > l16) p3 = 0.f;
                }
                pf[qg][tt] = pack_bf16x4(p0, p1, p2, p3);
                // l on the MFMA pipe (A=ones => all C rows = row-sum)
                Ol[qg] = MFMA16(ones4, pf[qg][tt], Ol[qg]);
            }
        }
        // O^T += V^T * P^T, 16-key chunks, P from registers
        __builtin_amdgcn_s_setprio(1);
#pragma unroll
        for (int tt = 0; tt < 4; tt++) {
            if (k0 + tt * 16 < qr0 + 32) {
#pragma unroll
                for (int dt = 0; dt < 4; dt++) {
                    bf16x4 va = *(const bf16x4*)&VC[voff[tt][dt]];
                    O[0][dt] = MFMA16(va, pf[0][tt], O[0][dt]);
                    O[1][dt] = MFMA16(va, pf[1][tt], O[1][dt]);
                }
            }
        }
        __builtin_amdgcn_s_setprio(0);
    };

    for (int kt = kt0; kt <= kt_end; ) {
        step(kt, Ks[0], Vs[0], Ks[1], Vs[1]); kt++;
        if (kt > kt_end) break;
        step(kt, Ks[1], Vs[1], Ks[0], Vs[0]); kt++;
    }

#pragma unroll
    for (int qg = 0; qg < 2; qg++) {
        float l = Ol[qg][0];
        if (!partial) {
            float inv = 1.0f / l;
#pragma unroll
            for (int dt = 0; dt < 4; dt++) {
                ushort4 o;
                o.x = f2bf(O[qg][dt][0] * inv);
                o.y = f2bf(O[qg][dt][1] * inv);
                o.z = f2bf(O[qg][dt][2] * inv);
                o.w = f2bf(O[qg][dt][3] * inv);
                *(ushort4*)(attn_bf + (size_t)(qr0 + qg * 16 + l16) * D_MODEL + h * 64 + dt * 16 + quad * 4) = o;
            }
        } else {
            int uid = h * 72 + u;
            size_t ob = (size_t)uid * 8192;
            int qcol = w * 32 + qg * 16 + l16;
#pragma unroll
            for (int dt = 0; dt < 4; dt++)
#pragma unroll
                for (int r = 0; r < 4; r++)
                    part_O[ob + (size_t)(dt * 16 + quad * 4 + r) * 128 + qcol] = O[qg][dt][r];
            if (quad == 0) part_l[uid * 128 + qcol] = l;
        }
    }
}

// ------------- combine partials: sum chunks, normalize, -> attn_bf -------------
__global__ __launch_bounds__(256) void combine_kernel(const float* __restrict__ part_O,
                                                      const float* __restrict__ part_l,
                                                      unsigned short* __restrict__ attn_bf) {
    int Qt = 8 + blockIdx.x;       // 8..31
    int h  = blockIdx.y;
    int nc = (Qt + 8) >> 3;        // 2,3,4 chunks
    int t = threadIdx.x;
    int q = t & 127;
    int dh = (t >> 7) * 32;
    float l = 0.f;
    float acc[32];
#pragma unroll
    for (int d = 0; d < 32; d++) acc[d] = 0.f;
    for (int c = 0; c < nc; c++) {
        int r;
        if (Qt < 16)      r = 2 * (Qt - 8) + c;
        else if (Qt < 24) r = 16 + 3 * (Qt - 16) + c;
        else              r = 40 + 4 * (Qt - 24) + c;
        int uid = h * 72 + (71 - r);
        l += part_l[uid * 128 + q];
        const float* po = part_O + (size_t)uid * 8192 + (size_t)dh * 128 + q;
#pragma unroll
        for (int d = 0; d < 32; d++) acc[d] += po[d * 128];
    }
    float inv = 1.0f / l;
    unsigned short* op = attn_bf + (size_t)(Qt * 128 + q) * D_MODEL + h * 64 + dh;
#pragma unroll
    for (int d = 0; d < 32; d++) op[d] = f2bf(acc[d] * inv);
}

extern "C" void kernel_launch(void* const* d_in, const int* in_sizes, int n_in,
                              void* d_out, int out_size, void* d_ws, size_t ws_size,
                              hipStream_t stream) {
    const float* x     = (const float*)d_in[0];
    const float* w_qkv = (const float*)d_in[1];
    const float* w_out = (const float*)d_in[2];
    const float* ln_g  = (const float*)d_in[3];
    const float* ln_b  = (const float*)d_in[4];

    float* out   = (float*)d_out;                       // [4096,1024]
    float* out_k = (float*)d_out + 4194304;             // [16,4096,64]
    float* out_v = (float*)d_out + 8388608;             // [16,4096,64]

    char* ws = (char*)d_ws;
    const size_t MiB = 1048576;
    float*          qkv_f   = (float*)(ws);                    // [4096,3072] fp32   @0..48 (dead after rope)
    unsigned short* h_bf    = (unsigned short*)(ws + 48*MiB);  // bf16 @48..56 (dead after gemm1)
    unsigned short* wqkvT   = (unsigned short*)(ws + 56*MiB);  // bf16 @56..62 (dead after gemm1)
    unsigned short* q_bf    = (unsigned short*)(ws + 48*MiB);  // [16,4096,64] bf16  @48..56
    unsigned short* k_bf    = (unsigned short*)(ws + 56*MiB);  // [16,4096,64] bf16  @56..64
    unsigned short* vt_bf   = (unsigned short*)(ws + 64*MiB);  // [16,64,4096] bf16  @64..72
    unsigned short* attn_bf = (unsigned short*)(ws);           // [4096,1024] bf16   @0..8
    float*          part_l  = (float*)(ws + 8*MiB);            // [1152][128] fp32   @8..8.56
    float*          part_O  = (float*)(ws + 9*MiB);            // [1152][64][128]    @9..46.7
    unsigned short* woutT   = (unsigned short*)(ws + 72*MiB);  // [1024,1024] bf16   @72..74

    transpose_cvt<<<dim3(16, 48), 256, 0, stream>>>(w_qkv, wqkvT, D_MODEL, QKV_COLS);
    transpose_cvt<<<dim3(16, 16), 256, 0, stream>>>(w_out, woutT, D_MODEL, D_MODEL);
    ln_kernel<<<N_SEQ, 256, 0, stream>>>(x, ln_g, ln_b, h_bf);
    gemm_bt128<<<dim3(32, 24), 256, 0, stream>>>(h_bf, wqkvT, qkv_f, N_SEQ, QKV_COLS, D_MODEL);
    rope_cache_kernel<<<dim3(64, 16), 256, 0, stream>>>(qkv_f, out_k, out_v, q_bf, k_bf, vt_bf);
    flash_mfma<<<1280, 256, 0, stream>>>(q_bf, k_bf, vt_bf, attn_bf, part_O, part_l);
    combine_kernel<<<dim3(24, 16), 256, 0, stream>>>(part_O, part_l, attn_bf);
    gemm_bt128<<<dim3(32, 8), 256, 0, stream>>>(attn_bf, woutT, out, N_SEQ, D_MODEL, D_MODEL);
}

// Round 5
// 265.972 us; speedup vs baseline: 1.2006x; 1.2006x over previous
//
#include <hip/hip_runtime.h>
#include <math.h>

#define D_MODEL 1024
#define N_SEQ   4096
#define N_HEADS 16
#define DHEAD   64
#define QKV_COLS 3072   // 3 * 1024

typedef short bf16x8 __attribute__((ext_vector_type(8)));
typedef short bf16x4 __attribute__((ext_vector_type(4)));
typedef float f32x4  __attribute__((ext_vector_type(4)));

#define MFMA32(a, b, c) __builtin_amdgcn_mfma_f32_16x16x32_bf16(a, b, c, 0, 0, 0)
// v_mfma_f32_16x16x16_bf16 (2/2/4 regs) — gfx90a-lineage builtin, valid on gfx950.
#define MFMA16(a, b, c) __builtin_amdgcn_mfma_f32_16x16x16bf16_1k(a, b, c, 0, 0, 0)

static __device__ __forceinline__ unsigned short f2bf(float f) {
    union { float f; unsigned u; } v; v.f = f;
    unsigned r = (v.u + 0x7fffu + ((v.u >> 16) & 1u)) >> 16;
    return (unsigned short)r;
}

// pack 4 floats -> 4 bf16 by truncation (1 v_perm_b32 per pair)
static __device__ __forceinline__ bf16x4 pack_bf16x4(float a, float b, float c, float d) {
    union { float f; unsigned u; } x0, x1, x2, x3;
    x0.f = a; x1.f = b; x2.f = c; x3.f = d;
    union { unsigned u[2]; bf16x4 v; } r;
    r.u[0] = __builtin_amdgcn_perm(x1.u, x0.u, 0x07060302u);
    r.u[1] = __builtin_amdgcn_perm(x3.u, x2.u, 0x07060302u);
    return r.v;
}

typedef __attribute__((address_space(1))) const void* gas_t;
typedef __attribute__((address_space(3))) void* las_t;
static __device__ __forceinline__ void load_lds16(const unsigned short* g, unsigned short* l) {
    __builtin_amdgcn_global_load_lds((gas_t)g, (las_t)l, 16, 0, 0);
}

// fast sin/cos: revolution-space reduction + native v_sin/v_cos.
// phase err ~2.4e-4 rad at theta~4096 — far below bf16 output precision.
static __device__ __forceinline__ void fast_sincos(float theta, float* s, float* c) {
    float rev = theta * 0.15915494309189535f;   // 1/(2*pi)
    rev = rev - floorf(rev);                    // [0,1): inside native valid range
    float a = rev * 6.283185307179586f;
    *s = __sinf(a);
    *c = __cosf(a);
}

// ---------------- LayerNorm: one block per row, bf16 out ----------------
__global__ __launch_bounds__(256) void ln_kernel(const float* __restrict__ x,
                                                 const float* __restrict__ g,
                                                 const float* __restrict__ b,
                                                 unsigned short* __restrict__ h) {
    int row = blockIdx.x;
    int t = threadIdx.x;
    float4 v = ((const float4*)(x + (size_t)row * D_MODEL))[t];
    float s  = v.x + v.y + v.z + v.w;
    float ss = v.x*v.x + v.y*v.y + v.z*v.z + v.w*v.w;
    for (int off = 32; off; off >>= 1) {
        s  += __shfl_down(s, off);
        ss += __shfl_down(ss, off);
    }
    __shared__ float sm[4], ssm[4];
    __shared__ float mu_s, rs_s;
    int wave = t >> 6, lane = t & 63;
    if (lane == 0) { sm[wave] = s; ssm[wave] = ss; }
    __syncthreads();
    if (t == 0) {
        float S = 0.f, SS = 0.f;
        for (int w = 0; w < 4; w++) { S += sm[w]; SS += ssm[w]; }
        float mu = S / D_MODEL;
        float var = SS / D_MODEL - mu * mu;
        mu_s = mu;
        rs_s = rsqrtf(var + 1e-5f);
    }
    __syncthreads();
    float mu = mu_s, rs = rs_s;
    float4 gv = ((const float4*)g)[t];
    float4 bv = ((const float4*)b)[t];
    ushort4 o;
    o.x = f2bf((v.x - mu) * rs * gv.x + bv.x);
    o.y = f2bf((v.y - mu) * rs * gv.y + bv.y);
    o.z = f2bf((v.z - mu) * rs * gv.z + bv.z);
    o.w = f2bf((v.w - mu) * rs * gv.w + bv.w);
    *(ushort4*)(h + (size_t)row * D_MODEL + t * 4) = o;
}

// ------------- transpose + fp32->bf16: W[K][N] -> Wt[N][K] -------------
__global__ __launch_bounds__(256) void transpose_cvt(const float* __restrict__ W,
                                                     unsigned short* __restrict__ Wt,
                                                     int K, int N) {
    __shared__ float tile[64][65];
    int k0 = blockIdx.x * 64, n0 = blockIdx.y * 64;
    int t = threadIdx.x;
#pragma unroll
    for (int p = 0; p < 16; p++) {
        int idx = p * 256 + t;
        int r = idx >> 6, c = idx & 63;
        tile[r][c] = W[(size_t)(k0 + r) * N + n0 + c];
    }
    __syncthreads();
#pragma unroll
    for (int p = 0; p < 16; p++) {
        int idx = p * 256 + t;
        int r2 = idx >> 6, c2 = idx & 63;
        Wt[(size_t)(n0 + r2) * K + k0 + c2] = f2bf(tile[c2][r2]);
    }
}

// ---- m97-style MFMA bf16 GEMM: C[M,N] = A[M,K] * Bt[N,K]^T, fp32 out ----
__global__ __launch_bounds__(256) void gemm_bt128(const unsigned short* __restrict__ A,
                                                  const unsigned short* __restrict__ Bt,
                                                  float* __restrict__ C,
                                                  int M, int N, int K) {
    __shared__ unsigned short As[128 * 32];
    __shared__ unsigned short Bs[128 * 32];
    int t = threadIdx.x;
    int w = t >> 6, lane = t & 63;
    int l16 = lane & 15, quad = lane >> 4;
    int wr = w >> 1, wc = w & 1;
    int m0 = blockIdx.x * 128, n0 = blockIdx.y * 128;
    int srow = lane >> 2, scol = (lane & 3) * 8;
    int c0 = w * 2, c1 = c0 + 1;

    f32x4 acc[4][4] = {};

    for (int k0 = 0; k0 < K; k0 += 32) {
        __syncthreads();
        load_lds16(A  + (size_t)(m0 + c0 * 16 + srow) * K + k0 + scol, &As[c0 * 512 + lane * 8]);
        load_lds16(A  + (size_t)(m0 + c1 * 16 + srow) * K + k0 + scol, &As[c1 * 512 + lane * 8]);
        load_lds16(Bt + (size_t)(n0 + c0 * 16 + srow) * K + k0 + scol, &Bs[c0 * 512 + lane * 8]);
        load_lds16(Bt + (size_t)(n0 + c1 * 16 + srow) * K + k0 + scol, &Bs[c1 * 512 + lane * 8]);
        __syncthreads();
        bf16x8 a[4], b[4];
#pragma unroll
        for (int mt = 0; mt < 4; mt++)
            a[mt] = *(const bf16x8*)&As[(wr * 64 + mt * 16 + l16) * 32 + quad * 8];
#pragma unroll
        for (int nt = 0; nt < 4; nt++)
            b[nt] = *(const bf16x8*)&Bs[(wc * 64 + nt * 16 + l16) * 32 + quad * 8];
#pragma unroll
        for (int mt = 0; mt < 4; mt++)
#pragma unroll
            for (int nt = 0; nt < 4; nt++)
                acc[mt][nt] = MFMA32(a[mt], b[nt], acc[mt][nt]);
    }
#pragma unroll
    for (int mt = 0; mt < 4; mt++)
#pragma unroll
        for (int nt = 0; nt < 4; nt++)
#pragma unroll
            for (int r = 0; r < 4; r++)
                C[(size_t)(m0 + wr * 64 + mt * 16 + quad * 4 + r) * N + n0 + wc * 64 + nt * 16 + l16] =
                    acc[mt][nt][r];
}

// --------- rope + caches. grid (64 ntiles, 16 heads), 256 thr ----------
// q_bf is PRE-SCALED by 0.125*log2(e) so flash can use exp2f(S) directly
// (removes 32 v_mul per tile per wave there). k_bf/out_k/out_v unscaled.
// powf -> exp2f, sincosf -> native v_sin/v_cos (libcall VALU diet).
__global__ __launch_bounds__(256) void rope_cache_kernel(const float* __restrict__ qkv,
                                                         float* __restrict__ out_k,
                                                         float* __restrict__ out_v,
                                                         unsigned short* __restrict__ q_bf,
                                                         unsigned short* __restrict__ k_bf,
                                                         unsigned short* __restrict__ vt_bf) {
    __shared__ unsigned short Vt[64 * 72];
    int nt = blockIdx.x, h = blockIdx.y;
    int n0 = nt * 64;
    int t = threadIdx.x;
    int row = t >> 2;
    int n = n0 + row;
    const float* src = qkv + (size_t)n * QKV_COLS + h * 64;
    size_t nd_base = ((size_t)h * N_SEQ + n) * 64;
    const float QSCALE = 0.18033688011112042f;   // 0.125 * log2(e)
    const float NL2_32 = -0.41524101186092029f;  // -log2(10000)/32
#pragma unroll
    for (int j = 0; j < 4; j++) {
        int c = (t & 3) * 4 + j * 16;
        float4 q4 = *(const float4*)(src + c);
        float4 k4 = *(const float4*)(src + 1024 + c);
        float4 v4 = *(const float4*)(src + 2048 + c);
        *(float4*)(out_k + nd_base + c) = k4;
        *(float4*)(out_v + nd_base + c) = v4;
        float i0 = (float)(c >> 1), i1 = i0 + 1.f;
        float if0 = exp2f(i0 * NL2_32);          // 10000^(-i0/32)
        float if1 = exp2f(i1 * NL2_32);
        float s0, c0s, s1, c1s;
        fast_sincos((float)n * if0, &s0, &c0s);
        fast_sincos((float)n * if1, &s1, &c1s);
        ushort4 qo, ko;
        qo.x = f2bf((q4.x * c0s - q4.y * s0) * QSCALE);
        qo.y = f2bf((q4.y * c0s + q4.x * s0) * QSCALE);
        qo.z = f2bf((q4.z * c1s - q4.w * s1) * QSCALE);
        qo.w = f2bf((q4.w * c1s + q4.z * s1) * QSCALE);
        ko.x = f2bf(k4.x * c0s - k4.y * s0); ko.y = f2bf(k4.y * c0s + k4.x * s0);
        ko.z = f2bf(k4.z * c1s - k4.w * s1); ko.w = f2bf(k4.w * c1s + k4.z * s1);
        *(ushort4*)(q_bf + nd_base + c) = qo;
        *(ushort4*)(k_bf + nd_base + c) = ko;
        ushort4 vo;
        vo.x = f2bf(v4.x); vo.y = f2bf(v4.y); vo.z = f2bf(v4.z); vo.w = f2bf(v4.w);
        *(ushort4*)&Vt[row * 72 + c] = vo;
    }
    __syncthreads();
    int d = t >> 2;
    int nb = (t & 3) * 16;
    unsigned short tmp[16];
#pragma unroll
    for (int i = 0; i < 16; i++) tmp[i] = Vt[(nb + i) * 72 + d];
    unsigned short* dst = vt_bf + ((size_t)h * DHEAD + d) * N_SEQ + n0 + nb;
#pragma unroll
    for (int i = 0; i < 16; i++) dst[i] = tmp[i];
}

// ------------- MFMA flash attention (causal, S^T form, split-K) -------------
// KNOWN-GOOD r1 scheduling: STATIC 1280 blocks, heavy-first natural order,
// h in low 4 bits (head->XCD L2 affinity: FETCH ~12.5 MB; r3 dynamic queue
// broke this -> 77 MB). launch_bounds(256,3): (256,5) in r4 caused scratch
// spills (VGPR 48, +24MB write / +17MB fetch of spill traffic, 1.6x slower).
// u<72: partial chunk (Qt>=8, 16-ktile chunk), writes fp32 O^T partial + l.
// u>=72: Qt<8, full range, writes attn direct. 2-phase double-buffered LDS;
// l accumulated on MFMA pipe via ones-row trick. Q pre-scaled -> exp2f direct.
__global__ __launch_bounds__(256, 3) void flash_mfma(const unsigned short* __restrict__ q_bf,
                                                     const unsigned short* __restrict__ k_bf,
                                                     const unsigned short* __restrict__ vt_bf,
                                                     unsigned short* __restrict__ attn_bf,
                                                     float* __restrict__ part_O,
                                                     float* __restrict__ part_l) {
    int idx = blockIdx.x;
    int h = idx & 15;                  // heads in low bits -> spread over XCDs
    int u = idx >> 4;                  // 0..79, heavy-first
    int Qt, cc;
    bool partial = (u < 72);
    if (partial) {
        int r = 71 - u;
        if (r < 16)      { Qt = 8 + (r >> 1); cc = r & 1; }
        else if (r < 40) { int q3 = r - 16; int d3 = q3 / 3; Qt = 16 + d3; cc = q3 - 3 * d3; }
        else             { int q4 = r - 40; Qt = 24 + (q4 >> 2); cc = q4 & 3; }
    } else { Qt = 79 - u; cc = 0; }
    int kt0 = cc * 16;
    int kt_end = min(kt0 + 15, 2 * Qt + 1);

    int t = threadIdx.x;
    int w = t >> 6, lane = t & 63;
    int l16 = lane & 15, quad = lane >> 4;
    int sw = l16 & 7;

    __shared__ unsigned short Ks[2][4096];   // 2 x 8KB, double-buffered
    __shared__ unsigned short Vs[2][4096];

    int qr0 = Qt * 128 + w * 32;
    const unsigned short* Kg = k_bf + (size_t)h * N_SEQ * DHEAD;
    const unsigned short* Vg = vt_bf + (size_t)h * DHEAD * N_SEQ;

    bf16x8 bq[2][2];
#pragma unroll
    for (int qg = 0; qg < 2; qg++) {
        const unsigned short* qp = q_bf + ((size_t)h * N_SEQ + qr0 + qg * 16 + l16) * 64 + quad * 8;
        bq[qg][0] = *(const bf16x8*)(qp);
        bq[qg][1] = *(const bf16x8*)(qp + 32);
    }
    f32x4 O[2][4] = {};
    f32x4 Ol[2] = {};                  // row-sum accumulator: l = sum_k P (ones-MFMA)
    int my_kmax = (qr0 + 31) >> 6;

    int srow = t >> 3;
    int scol = ((t & 7) ^ (srow & 7)) * 8;

    // ---- loop-invariant LDS fragment offsets (hoisted; static-indexed) ----
    int koffA[4], koffB[4];
#pragma unroll
    for (int tt = 0; tt < 4; tt++) {
        int krow = tt * 16 + l16;
        koffA[tt] = krow * 64 + ((quad ^ sw) * 8);
        koffB[tt] = krow * 64 + (((quad + 4) ^ sw) * 8);
    }
    int voff[4][4];
#pragma unroll
    for (int tt = 0; tt < 4; tt++)
#pragma unroll
        for (int dt = 0; dt < 4; dt++)
            voff[tt][dt] = (dt * 16 + l16) * 64 +
                           (((2 * tt + (quad >> 1)) ^ sw) * 8) + (quad & 1) * 4;

    // ---- staging pointers (advance by constants each tile) ----
    const unsigned short* kg0 = Kg + (size_t)(kt0 * 64 + srow) * 64 + scol;
    const unsigned short* kg1 = kg0 + 2048;                 // +32 rows
    const unsigned short* vg0 = Vg + (size_t)srow * N_SEQ + kt0 * 64 + scol;
    const unsigned short* vg1 = vg0 + (size_t)32 * N_SEQ;   // +32 d-rows

    const bf16x4 ones4 = {(short)0x3F80, (short)0x3F80, (short)0x3F80, (short)0x3F80};

    // prologue: stage kt0 into buffer 0
    load_lds16(kg0, &Ks[0][t * 8]);
    load_lds16(kg1, &Ks[0][t * 8 + 2048]);
    load_lds16(vg0, &Vs[0][t * 8]);
    load_lds16(vg1, &Vs[0][t * 8 + 2048]);
    kg0 += 4096; kg1 += 4096; vg0 += 64; vg1 += 64;

    // one step: barrier (drains prev stage + prev reads), issue next stage,
    // compute current buffer. Compile-time buffer bases fold into offsets.
    auto step = [&](int kt, const unsigned short* KC, const unsigned short* VC,
                    unsigned short* KN, unsigned short* VN) {
        __syncthreads();
        if (kt < kt_end) {
            load_lds16(kg0, KN + t * 8);
            load_lds16(kg1, KN + t * 8 + 2048);
            load_lds16(vg0, VN + t * 8);
            load_lds16(vg1, VN + t * 8 + 2048);
            kg0 += 4096; kg1 += 4096; vg0 += 64; vg1 += 64;
        }
        if (kt > my_kmax) return;
        int k0 = kt << 6;

        bf16x4 pf[2][4];
#pragma unroll
        for (int tt = 0; tt < 4; tt++) {
            int kbase = k0 + tt * 16;
            bf16x4 pz = (bf16x4){0, 0, 0, 0};
            if (kbase >= qr0 + 32) { pf[0][tt] = pz; pf[1][tt] = pz; continue; }
            bf16x8 kf0 = *(const bf16x8*)&KC[koffA[tt]];
            bf16x8 kf1 = *(const bf16x8*)&KC[koffB[tt]];
#pragma unroll
            for (int qg = 0; qg < 2; qg++) {
                int qb = qr0 + qg * 16;
                if (kbase > qb) { pf[qg][tt] = pz; continue; }
                f32x4 s = (f32x4){0.f, 0.f, 0.f, 0.f};
                s = MFMA32(kf0, bq[qg][0], s);
                s = MFMA32(kf1, bq[qg][1], s);
                float p0 = exp2f(s[0]);     // Q pre-scaled by 0.125*log2(e)
                float p1 = exp2f(s[1]);
                float p2 = exp2f(s[2]);
                float p3 = exp2f(s[3]);
                if (kbase == qb) {   // diagonal tile: mask key > q
                    if (quad * 4 + 0 > l16) p0 = 0.f;
                    if (quad * 4 + 1 > l16) p1 = 0.f;
                    if (quad * 4 + 2 > l16) p2 = 0.f;
                    if (quad * 4 + 3 > l16) p3 = 0.f;
                }
                pf[qg][tt] = pack_bf16x4(p0, p1, p2, p3);
                // l on the MFMA pipe (A=ones => all C rows = row-sum)
                Ol[qg] = MFMA16(ones4, pf[qg][tt], Ol[qg]);
            }
        }
        // O^T += V^T * P^T, 16-key chunks, P from registers
        __builtin_amdgcn_s_setprio(1);
#pragma unroll
        for (int tt = 0; tt < 4; tt++) {
            if (k0 + tt * 16 < qr0 + 32) {
#pragma unroll
                for (int dt = 0; dt < 4; dt++) {
                    bf16x4 va = *(const bf16x4*)&VC[voff[tt][dt]];
                    O[0][dt] = MFMA16(va, pf[0][tt], O[0][dt]);
                    O[1][dt] = MFMA16(va, pf[1][tt], O[1][dt]);
                }
            }
        }
        __builtin_amdgcn_s_setprio(0);
    };

    for (int kt = kt0; kt <= kt_end; ) {
        step(kt, Ks[0], Vs[0], Ks[1], Vs[1]); kt++;
        if (kt > kt_end) break;
        step(kt, Ks[1], Vs[1], Ks[0], Vs[0]); kt++;
    }

#pragma unroll
    for (int qg = 0; qg < 2; qg++) {
        float l = Ol[qg][0];
        if (!partial) {
            float inv = 1.0f / l;
#pragma unroll
            for (int dt = 0; dt < 4; dt++) {
                ushort4 o;
                o.x = f2bf(O[qg][dt][0] * inv);
                o.y = f2bf(O[qg][dt][1] * inv);
                o.z = f2bf(O[qg][dt][2] * inv);
                o.w = f2bf(O[qg][dt][3] * inv);
                *(ushort4*)(attn_bf + (size_t)(qr0 + qg * 16 + l16) * D_MODEL + h * 64 + dt * 16 + quad * 4) = o;
            }
        } else {
            int uid = h * 72 + u;
            size_t ob = (size_t)uid * 8192;
            int qcol = w * 32 + qg * 16 + l16;
#pragma unroll
            for (int dt = 0; dt < 4; dt++)
#pragma unroll
                for (int r = 0; r < 4; r++)
                    part_O[ob + (size_t)(dt * 16 + quad * 4 + r) * 128 + qcol] = O[qg][dt][r];
            if (quad == 0) part_l[uid * 128 + qcol] = l;
        }
    }
}

// ------------- combine partials: sum chunks, normalize, -> attn_bf -------------
__global__ __launch_bounds__(256) void combine_kernel(const float* __restrict__ part_O,
                                                      const float* __restrict__ part_l,
                                                      unsigned short* __restrict__ attn_bf) {
    int Qt = 8 + blockIdx.x;       // 8..31
    int h  = blockIdx.y;
    int nc = (Qt + 8) >> 3;        // 2,3,4 chunks
    int t = threadIdx.x;
    int q = t & 127;
    int dh = (t >> 7) * 32;
    float l = 0.f;
    float acc[32];
#pragma unroll
    for (int d = 0; d < 32; d++) acc[d] = 0.f;
    for (int c = 0; c < nc; c++) {
        int r;
        if (Qt < 16)      r = 2 * (Qt - 8) + c;
        else if (Qt < 24) r = 16 + 3 * (Qt - 16) + c;
        else              r = 40 + 4 * (Qt - 24) + c;
        int uid = h * 72 + (71 - r);
        l += part_l[uid * 128 + q];
        const float* po = part_O + (size_t)uid * 8192 + (size_t)dh * 128 + q;
#pragma unroll
        for (int d = 0; d < 32; d++) acc[d] += po[d * 128];
    }
    float inv = 1.0f / l;
    unsigned short* op = attn_bf + (size_t)(Qt * 128 + q) * D_MODEL + h * 64 + dh;
#pragma unroll
    for (int d = 0; d < 32; d++) op[d] = f2bf(acc[d] * inv);
}

extern "C" void kernel_launch(void* const* d_in, const int* in_sizes, int n_in,
                              void* d_out, int out_size, void* d_ws, size_t ws_size,
                              hipStream_t stream) {
    const float* x     = (const float*)d_in[0];
    const float* w_qkv = (const float*)d_in[1];
    const float* w_out = (const float*)d_in[2];
    const float* ln_g  = (const float*)d_in[3];
    const float* ln_b  = (const float*)d_in[4];

    float* out   = (float*)d_out;                       // [4096,1024]
    float* out_k = (float*)d_out + 4194304;             // [16,4096,64]
    float* out_v = (float*)d_out + 8388608;             // [16,4096,64]

    char* ws = (char*)d_ws;
    const size_t MiB = 1048576;
    float*          qkv_f   = (float*)(ws);                    // [4096,3072] fp32   @0..48 (dead after rope)
    unsigned short* h_bf    = (unsigned short*)(ws + 48*MiB);  // bf16 @48..56 (dead after gemm1)
    unsigned short* wqkvT   = (unsigned short*)(ws + 56*MiB);  // bf16 @56..62 (dead after gemm1)
    unsigned short* q_bf    = (unsigned short*)(ws + 48*MiB);  // [16,4096,64] bf16  @48..56
    unsigned short* k_bf    = (unsigned short*)(ws + 56*MiB);  // [16,4096,64] bf16  @56..64
    unsigned short* vt_bf   = (unsigned short*)(ws + 64*MiB);  // [16,64,4096] bf16  @64..72
    unsigned short* attn_bf = (unsigned short*)(ws);           // [4096,1024] bf16   @0..8
    float*          part_l  = (float*)(ws + 8*MiB);            // [1152][128] fp32   @8..8.56
    float*          part_O  = (float*)(ws + 9*MiB);            // [1152][64][128]    @9..46.7
    unsigned short* woutT   = (unsigned short*)(ws + 72*MiB);  // [1024,1024] bf16   @72..74

    transpose_cvt<<<dim3(16, 48), 256, 0, stream>>>(w_qkv, wqkvT, D_MODEL, QKV_COLS);
    transpose_cvt<<<dim3(16, 16), 256, 0, stream>>>(w_out, woutT, D_MODEL, D_MODEL);
    ln_kernel<<<N_SEQ, 256, 0, stream>>>(x, ln_g, ln_b, h_bf);
    gemm_bt128<<<dim3(32, 24), 256, 0, stream>>>(h_bf, wqkvT, qkv_f, N_SEQ, QKV_COLS, D_MODEL);
    rope_cache_kernel<<<dim3(64, 16), 256, 0, stream>>>(qkv_f, out_k, out_v, q_bf, k_bf, vt_bf);
    flash_mfma<<<1280, 256, 0, stream>>>(q_bf, k_bf, vt_bf, attn_bf, part_O, part_l);
    combine_kernel<<<dim3(24, 16), 256, 0, stream>>>(part_O, part_l, attn_bf);
    gemm_bt128<<<dim3(32, 8), 256, 0, stream>>>(attn_bf, woutT, out, N_SEQ, D_MODEL, D_MODEL);
}

// Round 6
// 258.456 us; speedup vs baseline: 1.2355x; 1.0291x over previous
//
#include <hip/hip_runtime.h>
#include <math.h>

#define D_MODEL 1024
#define N_SEQ   4096
#define N_HEADS 16
#define DHEAD   64
#define QKV_COLS 3072   // 3 * 1024

typedef short bf16x8 __attribute__((ext_vector_type(8)));
typedef short bf16x4 __attribute__((ext_vector_type(4)));
typedef float f32x4  __attribute__((ext_vector_type(4)));

#define MFMA32(a, b, c) __builtin_amdgcn_mfma_f32_16x16x32_bf16(a, b, c, 0, 0, 0)
// v_mfma_f32_16x16x16_bf16 (2/2/4 regs) — gfx90a-lineage builtin, valid on gfx950.
#define MFMA16(a, b, c) __builtin_amdgcn_mfma_f32_16x16x16bf16_1k(a, b, c, 0, 0, 0)

static __device__ __forceinline__ unsigned short f2bf(float f) {
    union { float f; unsigned u; } v; v.f = f;
    unsigned r = (v.u + 0x7fffu + ((v.u >> 16) & 1u)) >> 16;
    return (unsigned short)r;
}

// pack 4 floats -> 4 bf16 by truncation (1 v_perm_b32 per pair)
static __device__ __forceinline__ bf16x4 pack_bf16x4(float a, float b, float c, float d) {
    union { float f; unsigned u; } x0, x1, x2, x3;
    x0.f = a; x1.f = b; x2.f = c; x3.f = d;
    union { unsigned u[2]; bf16x4 v; } r;
    r.u[0] = __builtin_amdgcn_perm(x1.u, x0.u, 0x07060302u);
    r.u[1] = __builtin_amdgcn_perm(x3.u, x2.u, 0x07060302u);
    return r.v;
}

typedef __attribute__((address_space(1))) const void* gas_t;
typedef __attribute__((address_space(3))) void* las_t;
static __device__ __forceinline__ void load_lds16(const unsigned short* g, unsigned short* l) {
    __builtin_amdgcn_global_load_lds((gas_t)g, (las_t)l, 16, 0, 0);
}

// fast sin/cos: revolution-space reduction + native v_sin/v_cos.
// phase err ~2.4e-4 rad at theta~4096 — far below bf16 output precision.
static __device__ __forceinline__ void fast_sincos(float theta, float* s, float* c) {
    float rev = theta * 0.15915494309189535f;   // 1/(2*pi)
    rev = rev - floorf(rev);                    // [0,1): inside native valid range
    float a = rev * 6.283185307179586f;
    *s = __sinf(a);
    *c = __cosf(a);
}

// ---------------- LayerNorm: one block per row, bf16 out ----------------
__global__ __launch_bounds__(256) void ln_kernel(const float* __restrict__ x,
                                                 const float* __restrict__ g,
                                                 const float* __restrict__ b,
                                                 unsigned short* __restrict__ h) {
    int row = blockIdx.x;
    int t = threadIdx.x;
    float4 v = ((const float4*)(x + (size_t)row * D_MODEL))[t];
    float s  = v.x + v.y + v.z + v.w;
    float ss = v.x*v.x + v.y*v.y + v.z*v.z + v.w*v.w;
    for (int off = 32; off; off >>= 1) {
        s  += __shfl_down(s, off);
        ss += __shfl_down(ss, off);
    }
    __shared__ float sm[4], ssm[4];
    __shared__ float mu_s, rs_s;
    int wave = t >> 6, lane = t & 63;
    if (lane == 0) { sm[wave] = s; ssm[wave] = ss; }
    __syncthreads();
    if (t == 0) {
        float S = 0.f, SS = 0.f;
        for (int w = 0; w < 4; w++) { S += sm[w]; SS += ssm[w]; }
        float mu = S / D_MODEL;
        float var = SS / D_MODEL - mu * mu;
        mu_s = mu;
        rs_s = rsqrtf(var + 1e-5f);
    }
    __syncthreads();
    float mu = mu_s, rs = rs_s;
    float4 gv = ((const float4*)g)[t];
    float4 bv = ((const float4*)b)[t];
    ushort4 o;
    o.x = f2bf((v.x - mu) * rs * gv.x + bv.x);
    o.y = f2bf((v.y - mu) * rs * gv.y + bv.y);
    o.z = f2bf((v.z - mu) * rs * gv.z + bv.z);
    o.w = f2bf((v.w - mu) * rs * gv.w + bv.w);
    *(ushort4*)(h + (size_t)row * D_MODEL + t * 4) = o;
}

// --- transpose + fp32->bf16 for BOTH weights in one launch (K=1024 each) ---
// blockIdx.y < 48: w_qkv [1024][3072]; else: w_out [1024][1024].
__global__ __launch_bounds__(256) void transpose_cvt2(const float* __restrict__ Wa,
                                                      unsigned short* __restrict__ Ta,
                                                      const float* __restrict__ Wb,
                                                      unsigned short* __restrict__ Tb) {
    __shared__ float tile[64][65];
    int by = blockIdx.y;
    const float* W; unsigned short* Wt; int N, n0;
    if (by < 48) { W = Wa; Wt = Ta; N = QKV_COLS; n0 = by * 64; }
    else         { W = Wb; Wt = Tb; N = D_MODEL;  n0 = (by - 48) * 64; }
    const int K = D_MODEL;
    int k0 = blockIdx.x * 64;
    int t = threadIdx.x;
#pragma unroll
    for (int p = 0; p < 16; p++) {
        int idx = p * 256 + t;
        int r = idx >> 6, c = idx & 63;
        tile[r][c] = W[(size_t)(k0 + r) * N + n0 + c];
    }
    __syncthreads();
#pragma unroll
    for (int p = 0; p < 16; p++) {
        int idx = p * 256 + t;
        int r2 = idx >> 6, c2 = idx & 63;
        Wt[(size_t)(n0 + r2) * K + k0 + c2] = f2bf(tile[c2][r2]);
    }
}

// ---- m97-style MFMA bf16 GEMM: C[M,N] = A[M,K] * Bt[N,K]^T, fp32 out ----
__global__ __launch_bounds__(256) void gemm_bt128(const unsigned short* __restrict__ A,
                                                  const unsigned short* __restrict__ Bt,
                                                  float* __restrict__ C,
                                                  int M, int N, int K) {
    __shared__ unsigned short As[128 * 32];
    __shared__ unsigned short Bs[128 * 32];
    int t = threadIdx.x;
    int w = t >> 6, lane = t & 63;
    int l16 = lane & 15, quad = lane >> 4;
    int wr = w >> 1, wc = w & 1;
    int m0 = blockIdx.x * 128, n0 = blockIdx.y * 128;
    int srow = lane >> 2, scol = (lane & 3) * 8;
    int c0 = w * 2, c1 = c0 + 1;

    f32x4 acc[4][4] = {};

    for (int k0 = 0; k0 < K; k0 += 32) {
        __syncthreads();
        load_lds16(A  + (size_t)(m0 + c0 * 16 + srow) * K + k0 + scol, &As[c0 * 512 + lane * 8]);
        load_lds16(A  + (size_t)(m0 + c1 * 16 + srow) * K + k0 + scol, &As[c1 * 512 + lane * 8]);
        load_lds16(Bt + (size_t)(n0 + c0 * 16 + srow) * K + k0 + scol, &Bs[c0 * 512 + lane * 8]);
        load_lds16(Bt + (size_t)(n0 + c1 * 16 + srow) * K + k0 + scol, &Bs[c1 * 512 + lane * 8]);
        __syncthreads();
        bf16x8 a[4], b[4];
#pragma unroll
        for (int mt = 0; mt < 4; mt++)
            a[mt] = *(const bf16x8*)&As[(wr * 64 + mt * 16 + l16) * 32 + quad * 8];
#pragma unroll
        for (int nt = 0; nt < 4; nt++)
            b[nt] = *(const bf16x8*)&Bs[(wc * 64 + nt * 16 + l16) * 32 + quad * 8];
#pragma unroll
        for (int mt = 0; mt < 4; mt++)
#pragma unroll
            for (int nt = 0; nt < 4; nt++)
                acc[mt][nt] = MFMA32(a[mt], b[nt], acc[mt][nt]);
    }
#pragma unroll
    for (int mt = 0; mt < 4; mt++)
#pragma unroll
        for (int nt = 0; nt < 4; nt++)
#pragma unroll
            for (int r = 0; r < 4; r++)
                C[(size_t)(m0 + wr * 64 + mt * 16 + quad * 4 + r) * N + n0 + wc * 64 + nt * 16 + l16] =
                    acc[mt][nt][r];
}

// ---- 64x128-tile variant (for small-N GEMMs needing more blocks/CU) ----
// Same fragment layout as gemm_bt128 with M-dim halved: 4 waves = 2x2 over
// (64 M, 128 N), wave tile 32x64, acc[2][4]. Used for the output projection
// (M=4096,N=1024): grid (64,8)=512 blocks = 2/CU vs 1/CU at 128 tiles.
__global__ __launch_bounds__(256) void gemm_bt64(const unsigned short* __restrict__ A,
                                                 const unsigned short* __restrict__ Bt,
                                                 float* __restrict__ C,
                                                 int M, int N, int K) {
    __shared__ unsigned short As[64 * 32];
    __shared__ unsigned short Bs[128 * 32];
    int t = threadIdx.x;
    int w = t >> 6, lane = t & 63;
    int l16 = lane & 15, quad = lane >> 4;
    int wr = w >> 1, wc = w & 1;
    int m0 = blockIdx.x * 64, n0 = blockIdx.y * 128;
    int srow = lane >> 2, scol = (lane & 3) * 8;
    int c0 = w * 2, c1 = c0 + 1;
    int srow2 = t >> 2, scol2 = (t & 3) * 8;

    f32x4 acc[2][4] = {};

    for (int k0 = 0; k0 < K; k0 += 32) {
        __syncthreads();
        load_lds16(A  + (size_t)(m0 + srow2) * K + k0 + scol2, &As[t * 8]);
        load_lds16(Bt + (size_t)(n0 + c0 * 16 + srow) * K + k0 + scol, &Bs[c0 * 512 + lane * 8]);
        load_lds16(Bt + (size_t)(n0 + c1 * 16 + srow) * K + k0 + scol, &Bs[c1 * 512 + lane * 8]);
        __syncthreads();
        bf16x8 a[2], b[4];
#pragma unroll
        for (int mt = 0; mt < 2; mt++)
            a[mt] = *(const bf16x8*)&As[(wr * 32 + mt * 16 + l16) * 32 + quad * 8];
#pragma unroll
        for (int nt = 0; nt < 4; nt++)
            b[nt] = *(const bf16x8*)&Bs[(wc * 64 + nt * 16 + l16) * 32 + quad * 8];
#pragma unroll
        for (int mt = 0; mt < 2; mt++)
#pragma unroll
            for (int nt = 0; nt < 4; nt++)
                acc[mt][nt] = MFMA32(a[mt], b[nt], acc[mt][nt]);
    }
#pragma unroll
    for (int mt = 0; mt < 2; mt++)
#pragma unroll
        for (int nt = 0; nt < 4; nt++)
#pragma unroll
            for (int r = 0; r < 4; r++)
                C[(size_t)(m0 + wr * 32 + mt * 16 + quad * 4 + r) * N + n0 + wc * 64 + nt * 16 + l16] =
                    acc[mt][nt][r];
}

// --------- rope + caches. grid (64 ntiles, 16 heads), 256 thr ----------
// q_bf is PRE-SCALED by 0.125*log2(e) so flash can use exp2f(S) directly.
__global__ __launch_bounds__(256) void rope_cache_kernel(const float* __restrict__ qkv,
                                                         float* __restrict__ out_k,
                                                         float* __restrict__ out_v,
                                                         unsigned short* __restrict__ q_bf,
                                                         unsigned short* __restrict__ k_bf,
                                                         unsigned short* __restrict__ vt_bf) {
    __shared__ unsigned short Vt[64 * 72];
    int nt = blockIdx.x, h = blockIdx.y;
    int n0 = nt * 64;
    int t = threadIdx.x;
    int row = t >> 2;
    int n = n0 + row;
    const float* src = qkv + (size_t)n * QKV_COLS + h * 64;
    size_t nd_base = ((size_t)h * N_SEQ + n) * 64;
    const float QSCALE = 0.18033688011112042f;   // 0.125 * log2(e)
    const float NL2_32 = -0.41524101186092029f;  // -log2(10000)/32
#pragma unroll
    for (int j = 0; j < 4; j++) {
        int c = (t & 3) * 4 + j * 16;
        float4 q4 = *(const float4*)(src + c);
        float4 k4 = *(const float4*)(src + 1024 + c);
        float4 v4 = *(const float4*)(src + 2048 + c);
        *(float4*)(out_k + nd_base + c) = k4;
        *(float4*)(out_v + nd_base + c) = v4;
        float i0 = (float)(c >> 1), i1 = i0 + 1.f;
        float if0 = exp2f(i0 * NL2_32);          // 10000^(-i0/32)
        float if1 = exp2f(i1 * NL2_32);
        float s0, c0s, s1, c1s;
        fast_sincos((float)n * if0, &s0, &c0s);
        fast_sincos((float)n * if1, &s1, &c1s);
        ushort4 qo, ko;
        qo.x = f2bf((q4.x * c0s - q4.y * s0) * QSCALE);
        qo.y = f2bf((q4.y * c0s + q4.x * s0) * QSCALE);
        qo.z = f2bf((q4.z * c1s - q4.w * s1) * QSCALE);
        qo.w = f2bf((q4.w * c1s + q4.z * s1) * QSCALE);
        ko.x = f2bf(k4.x * c0s - k4.y * s0); ko.y = f2bf(k4.y * c0s + k4.x * s0);
        ko.z = f2bf(k4.z * c1s - k4.w * s1); ko.w = f2bf(k4.w * c1s + k4.z * s1);
        *(ushort4*)(q_bf + nd_base + c) = qo;
        *(ushort4*)(k_bf + nd_base + c) = ko;
        ushort4 vo;
        vo.x = f2bf(v4.x); vo.y = f2bf(v4.y); vo.z = f2bf(v4.z); vo.w = f2bf(v4.w);
        *(ushort4*)&Vt[row * 72 + c] = vo;
    }
    __syncthreads();
    int d = t >> 2;
    int nb = (t & 3) * 16;
    unsigned short tmp[16];
#pragma unroll
    for (int i = 0; i < 16; i++) tmp[i] = Vt[(nb + i) * 72 + d];
    unsigned short* dst = vt_bf + ((size_t)h * DHEAD + d) * N_SEQ + n0 + nb;
#pragma unroll
    for (int i = 0; i < 16; i++) dst[i] = tmp[i];
}

// ------------- MFMA flash attention (causal, S^T form, split-K) -------------
// FROZEN r5 config (best measured): STATIC 1280 blocks, heavy-first order,
// h in low 4 bits (head->XCD L2 affinity), launch_bounds(256,3), 2-phase
// double-buffered LDS, l on MFMA pipe via ones-row, Q pre-scaled -> exp2f.
__global__ __launch_bounds__(256, 3) void flash_mfma(const unsigned short* __restrict__ q_bf,
                                                     const unsigned short* __restrict__ k_bf,
                                                     const unsigned short* __restrict__ vt_bf,
                                                     unsigned short* __restrict__ attn_bf,
                                                     float* __restrict__ part_O,
                                                     float* __restrict__ part_l) {
    int idx = blockIdx.x;
    int h = idx & 15;                  // heads in low bits -> spread over XCDs
    int u = idx >> 4;                  // 0..79, heavy-first
    int Qt, cc;
    bool partial = (u < 72);
    if (partial) {
        int r = 71 - u;
        if (r < 16)      { Qt = 8 + (r >> 1); cc = r & 1; }
        else if (r < 40) { int q3 = r - 16; int d3 = q3 / 3; Qt = 16 + d3; cc = q3 - 3 * d3; }
        else             { int q4 = r - 40; Qt = 24 + (q4 >> 2); cc = q4 & 3; }
    } else { Qt = 79 - u; cc = 0; }
    int kt0 = cc * 16;
    int kt_end = min(kt0 + 15, 2 * Qt + 1);

    int t = threadIdx.x;
    int w = t >> 6, lane = t & 63;
    int l16 = lane & 15, quad = lane >> 4;
    int sw = l16 & 7;

    __shared__ unsigned short Ks[2][4096];   // 2 x 8KB, double-buffered
    __shared__ unsigned short Vs[2][4096];

    int qr0 = Qt * 128 + w * 32;
    const unsigned short* Kg = k_bf + (size_t)h * N_SEQ * DHEAD;
    const unsigned short* Vg = vt_bf + (size_t)h * DHEAD * N_SEQ;

    bf16x8 bq[2][2];
#pragma unroll
    for (int qg = 0; qg < 2; qg++) {
        const unsigned short* qp = q_bf + ((size_t)h * N_SEQ + qr0 + qg * 16 + l16) * 64 + quad * 8;
        bq[qg][0] = *(const bf16x8*)(qp);
        bq[qg][1] = *(const bf16x8*)(qp + 32);
    }
    f32x4 O[2][4] = {};
    f32x4 Ol[2] = {};                  // row-sum accumulator: l = sum_k P (ones-MFMA)
    int my_kmax = (qr0 + 31) >> 6;

    int srow = t >> 3;
    int scol = ((t & 7) ^ (srow & 7)) * 8;

    // ---- loop-invariant LDS fragment offsets (hoisted; static-indexed) ----
    int koffA[4], koffB[4];
#pragma unroll
    for (int tt = 0; tt < 4; tt++) {
        int krow = tt * 16 + l16;
        koffA[tt] = krow * 64 + ((quad ^ sw) * 8);
        koffB[tt] = krow * 64 + (((quad + 4) ^ sw) * 8);
    }
    int voff[4][4];
#pragma unroll
    for (int tt = 0; tt < 4; tt++)
#pragma unroll
        for (int dt = 0; dt < 4; dt++)
            voff[tt][dt] = (dt * 16 + l16) * 64 +
                           (((2 * tt + (quad >> 1)) ^ sw) * 8) + (quad & 1) * 4;

    // ---- staging pointers (advance by constants each tile) ----
    const unsigned short* kg0 = Kg + (size_t)(kt0 * 64 + srow) * 64 + scol;
    const unsigned short* kg1 = kg0 + 2048;                 // +32 rows
    const unsigned short* vg0 = Vg + (size_t)srow * N_SEQ + kt0 * 64 + scol;
    const unsigned short* vg1 = vg0 + (size_t)32 * N_SEQ;   // +32 d-rows

    const bf16x4 ones4 = {(short)0x3F80, (short)0x3F80, (short)0x3F80, (short)0x3F80};

    // prologue: stage kt0 into buffer 0
    load_lds16(kg0, &Ks[0][t * 8]);
    load_lds16(kg1, &Ks[0][t * 8 + 2048]);
    load_lds16(vg0, &Vs[0][t * 8]);
    load_lds16(vg1, &Vs[0][t * 8 + 2048]);
    kg0 += 4096; kg1 += 4096; vg0 += 64; vg1 += 64;

    // one step: barrier (drains prev stage + prev reads), issue next stage,
    // compute current buffer. Compile-time buffer bases fold into offsets.
    auto step = [&](int kt, const unsigned short* KC, const unsigned short* VC,
                    unsigned short* KN, unsigned short* VN) {
        __syncthreads();
        if (kt < kt_end) {
            load_lds16(kg0, KN + t * 8);
            load_lds16(kg1, KN + t * 8 + 2048);
            load_lds16(vg0, VN + t * 8);
            load_lds16(vg1, VN + t * 8 + 2048);
            kg0 += 4096; kg1 += 4096; vg0 += 64; vg1 += 64;
        }
        if (kt > my_kmax) return;
        int k0 = kt << 6;

        bf16x4 pf[2][4];
#pragma unroll
        for (int tt = 0; tt < 4; tt++) {
            int kbase = k0 + tt * 16;
            bf16x4 pz = (bf16x4){0, 0, 0, 0};
            if (kbase >= qr0 + 32) { pf[0][tt] = pz; pf[1][tt] = pz; continue; }
            bf16x8 kf0 = *(const bf16x8*)&KC[koffA[tt]];
            bf16x8 kf1 = *(const bf16x8*)&KC[koffB[tt]];
#pragma unroll
            for (int qg = 0; qg < 2; qg++) {
                int qb = qr0 + qg * 16;
                if (kbase > qb) { pf[qg][tt] = pz; continue; }
                f32x4 s = (f32x4){0.f, 0.f, 0.f, 0.f};
                s = MFMA32(kf0, bq[qg][0], s);
                s = MFMA32(kf1, bq[qg][1], s);
                float p0 = exp2f(s[0]);     // Q pre-scaled by 0.125*log2(e)
                float p1 = exp2f(s[1]);
                float p2 = exp2f(s[2]);
                float p3 = exp2f(s[3]);
                if (kbase == qb) {   // diagonal tile: mask key > q
                    if (quad * 4 + 0 > l16) p0 = 0.f;
                    if (quad * 4 + 1 > l16) p1 = 0.f;
                    if (quad * 4 + 2 > l16) p2 = 0.f;
                    if (quad * 4 + 3 > l16) p3 = 0.f;
                }
                pf[qg][tt] = pack_bf16x4(p0, p1, p2, p3);
                // l on the MFMA pipe (A=ones => all C rows = row-sum)
                Ol[qg] = MFMA16(ones4, pf[qg][tt], Ol[qg]);
            }
        }
        // O^T += V^T * P^T, 16-key chunks, P from registers
        __builtin_amdgcn_s_setprio(1);
#pragma unroll
        for (int tt = 0; tt < 4; tt++) {
            if (k0 + tt * 16 < qr0 + 32) {
#pragma unroll
                for (int dt = 0; dt < 4; dt++) {
                    bf16x4 va = *(const bf16x4*)&VC[voff[tt][dt]];
                    O[0][dt] = MFMA16(va, pf[0][tt], O[0][dt]);
                    O[1][dt] = MFMA16(va, pf[1][tt], O[1][dt]);
                }
            }
        }
        __builtin_amdgcn_s_setprio(0);
    };

    for (int kt = kt0; kt <= kt_end; ) {
        step(kt, Ks[0], Vs[0], Ks[1], Vs[1]); kt++;
        if (kt > kt_end) break;
        step(kt, Ks[1], Vs[1], Ks[0], Vs[0]); kt++;
    }

#pragma unroll
    for (int qg = 0; qg < 2; qg++) {
        float l = Ol[qg][0];
        if (!partial) {
            float inv = 1.0f / l;
#pragma unroll
            for (int dt = 0; dt < 4; dt++) {
                ushort4 o;
                o.x = f2bf(O[qg][dt][0] * inv);
                o.y = f2bf(O[qg][dt][1] * inv);
                o.z = f2bf(O[qg][dt][2] * inv);
                o.w = f2bf(O[qg][dt][3] * inv);
                *(ushort4*)(attn_bf + (size_t)(qr0 + qg * 16 + l16) * D_MODEL + h * 64 + dt * 16 + quad * 4) = o;
            }
        } else {
            int uid = h * 72 + u;
            size_t ob = (size_t)uid * 8192;
            int qcol = w * 32 + qg * 16 + l16;
#pragma unroll
            for (int dt = 0; dt < 4; dt++)
#pragma unroll
                for (int r = 0; r < 4; r++)
                    part_O[ob + (size_t)(dt * 16 + quad * 4 + r) * 128 + qcol] = O[qg][dt][r];
            if (quad == 0) part_l[uid * 128 + qcol] = l;
        }
    }
}

// ------------- combine partials: sum chunks, normalize, -> attn_bf -------------
// grid (24,16,2): z splits the 64 d-dims into 2 halves -> 768 blocks (3/CU),
// 16 d per thread (was 384 blocks / 32 d: occupancy-starved streaming 38MB).
__global__ __launch_bounds__(256) void combine_kernel(const float* __restrict__ part_O,
                                                      const float* __restrict__ part_l,
                                                      unsigned short* __restrict__ attn_bf) {
    int Qt = 8 + blockIdx.x;       // 8..31
    int h  = blockIdx.y;
    int nc = (Qt + 8) >> 3;        // 2,3,4 chunks
    int t = threadIdx.x;
    int q = t & 127;
    int dh = blockIdx.z * 32 + (t >> 7) * 16;
    float l = 0.f;
    float acc[16];
#pragma unroll
    for (int d = 0; d < 16; d++) acc[d] = 0.f;
    for (int c = 0; c < nc; c++) {
        int r;
        if (Qt < 16)      r = 2 * (Qt - 8) + c;
        else if (Qt < 24) r = 16 + 3 * (Qt - 16) + c;
        else              r = 40 + 4 * (Qt - 24) + c;
        int uid = h * 72 + (71 - r);
        l += part_l[uid * 128 + q];
        const float* po = part_O + (size_t)uid * 8192 + (size_t)dh * 128 + q;
#pragma unroll
        for (int d = 0; d < 16; d++) acc[d] += po[d * 128];
    }
    float inv = 1.0f / l;
    unsigned short* op = attn_bf + (size_t)(Qt * 128 + q) * D_MODEL + h * 64 + dh;
#pragma unroll
    for (int d = 0; d < 16; d++) op[d] = f2bf(acc[d] * inv);
}

extern "C" void kernel_launch(void* const* d_in, const int* in_sizes, int n_in,
                              void* d_out, int out_size, void* d_ws, size_t ws_size,
                              hipStream_t stream) {
    const float* x     = (const float*)d_in[0];
    const float* w_qkv = (const float*)d_in[1];
    const float* w_out = (const float*)d_in[2];
    const float* ln_g  = (const float*)d_in[3];
    const float* ln_b  = (const float*)d_in[4];

    float* out   = (float*)d_out;                       // [4096,1024]
    float* out_k = (float*)d_out + 4194304;             // [16,4096,64]
    float* out_v = (float*)d_out + 8388608;             // [16,4096,64]

    char* ws = (char*)d_ws;
    const size_t MiB = 1048576;
    float*          qkv_f   = (float*)(ws);                    // [4096,3072] fp32   @0..48 (dead after rope)
    unsigned short* h_bf    = (unsigned short*)(ws + 48*MiB);  // bf16 @48..56 (dead after gemm1)
    unsigned short* wqkvT   = (unsigned short*)(ws + 56*MiB);  // bf16 @56..62 (dead after gemm1)
    unsigned short* q_bf    = (unsigned short*)(ws + 48*MiB);  // [16,4096,64] bf16  @48..56
    unsigned short* k_bf    = (unsigned short*)(ws + 56*MiB);  // [16,4096,64] bf16  @56..64
    unsigned short* vt_bf   = (unsigned short*)(ws + 64*MiB);  // [16,64,4096] bf16  @64..72
    unsigned short* attn_bf = (unsigned short*)(ws);           // [4096,1024] bf16   @0..8
    float*          part_l  = (float*)(ws + 8*MiB);            // [1152][128] fp32   @8..8.56
    float*          part_O  = (float*)(ws + 9*MiB);            // [1152][64][128]    @9..46.7
    unsigned short* woutT   = (unsigned short*)(ws + 72*MiB);  // [1024,1024] bf16   @72..74

    transpose_cvt2<<<dim3(16, 64), 256, 0, stream>>>(w_qkv, wqkvT, w_out, woutT);
    ln_kernel<<<N_SEQ, 256, 0, stream>>>(x, ln_g, ln_b, h_bf);
    gemm_bt128<<<dim3(32, 24), 256, 0, stream>>>(h_bf, wqkvT, qkv_f, N_SEQ, QKV_COLS, D_MODEL);
    rope_cache_kernel<<<dim3(64, 16), 256, 0, stream>>>(qkv_f, out_k, out_v, q_bf, k_bf, vt_bf);
    flash_mfma<<<1280, 256, 0, stream>>>(q_bf, k_bf, vt_bf, attn_bf, part_O, part_l);
    combine_kernel<<<dim3(24, 16, 2), 256, 0, stream>>>(part_O, part_l, attn_bf);
    gemm_bt64<<<dim3(64, 8), 256, 0, stream>>>(attn_bf, woutT, out, N_SEQ, D_MODEL, D_MODEL);
}

// Round 7
// 255.502 us; speedup vs baseline: 1.2498x; 1.0116x over previous
//
#include <hip/hip_runtime.h>
#include <math.h>

#define D_MODEL 1024
#define N_SEQ   4096
#define N_HEADS 16
#define DHEAD   64
#define QKV_COLS 3072   // 3 * 1024

typedef short bf16x8 __attribute__((ext_vector_type(8)));
typedef short bf16x4 __attribute__((ext_vector_type(4)));
typedef float f32x4  __attribute__((ext_vector_type(4)));

#define MFMA32(a, b, c) __builtin_amdgcn_mfma_f32_16x16x32_bf16(a, b, c, 0, 0, 0)
// v_mfma_f32_16x16x16_bf16 (2/2/4 regs) — gfx90a-lineage builtin, valid on gfx950.
#define MFMA16(a, b, c) __builtin_amdgcn_mfma_f32_16x16x16bf16_1k(a, b, c, 0, 0, 0)

static __device__ __forceinline__ unsigned short f2bf(float f) {
    union { float f; unsigned u; } v; v.f = f;
    unsigned r = (v.u + 0x7fffu + ((v.u >> 16) & 1u)) >> 16;
    return (unsigned short)r;
}

// pack 4 floats -> 4 bf16 by truncation (1 v_perm_b32 per pair)
static __device__ __forceinline__ bf16x4 pack_bf16x4(float a, float b, float c, float d) {
    union { float f; unsigned u; } x0, x1, x2, x3;
    x0.f = a; x1.f = b; x2.f = c; x3.f = d;
    union { unsigned u[2]; bf16x4 v; } r;
    r.u[0] = __builtin_amdgcn_perm(x1.u, x0.u, 0x07060302u);
    r.u[1] = __builtin_amdgcn_perm(x3.u, x2.u, 0x07060302u);
    return r.v;
}

typedef __attribute__((address_space(1))) const void* gas_t;
typedef __attribute__((address_space(3))) void* las_t;
static __device__ __forceinline__ void load_lds16(const unsigned short* g, unsigned short* l) {
    __builtin_amdgcn_global_load_lds((gas_t)g, (las_t)l, 16, 0, 0);
}

// fast sin/cos: revolution-space reduction + native v_sin/v_cos.
// phase err ~2.4e-4 rad at theta~4096 — far below bf16 output precision.
static __device__ __forceinline__ void fast_sincos(float theta, float* s, float* c) {
    float rev = theta * 0.15915494309189535f;   // 1/(2*pi)
    rev = rev - floorf(rev);                    // [0,1): inside native valid range
    float a = rev * 6.283185307179586f;
    *s = __sinf(a);
    *c = __cosf(a);
}

// slot->u permutation for flash_mfma: blockIdx = 16*s + h. HW dispatch maps
// idx->XCD h%8, and each CU gets the 5 blocks with s = c+16k (fixed h). Job
// weights (ktiles): 48 jobs @16 + four sets {2,4,..,16}. This table gives
// every CU-class exactly 3x16 + an 18-sum pair = 66 tiles -> zero imbalance,
// h stays in low 4 bits (head->XCD L2 affinity preserved). Verified correct
// in r4 (passed); r4's regression was launch_bounds(256,5) VGPR spills, NOT
// this table (its FETCH 29.4MB = 12.4 clean + 17 spill-reads).
__constant__ unsigned char U_TAB[80] = {
    // k=0 (heavy)
    71,65,59,54,49,45,40,36,31,27,23,19,15,11,7,3,
    // k=1 (heavy)
    69,63,57,52,48,43,39,34,30,26,22,18,14,10,6,2,
    // k=2 (heavy)
    67,61,55,51,46,42,37,33,29,25,21,17,13,9,5,1,
    // k=3 (pair a: weights 2,4,6,8 per quarter)
    70,68,66,64,53,50,47,44,28,24,20,16,79,78,77,76,
    // k=4 (pair b: weights 16,14,12,10 per quarter)
    56,58,60,62,32,35,38,41,0,4,8,12,72,73,74,75
};

// ---------------- LayerNorm: one block per row, bf16 out ----------------
__global__ __launch_bounds__(256) void ln_kernel(const float* __restrict__ x,
                                                 const float* __restrict__ g,
                                                 const float* __restrict__ b,
                                                 unsigned short* __restrict__ h) {
    int row = blockIdx.x;
    int t = threadIdx.x;
    float4 v = ((const float4*)(x + (size_t)row * D_MODEL))[t];
    float s  = v.x + v.y + v.z + v.w;
    float ss = v.x*v.x + v.y*v.y + v.z*v.z + v.w*v.w;
    for (int off = 32; off; off >>= 1) {
        s  += __shfl_down(s, off);
        ss += __shfl_down(ss, off);
    }
    __shared__ float sm[4], ssm[4];
    __shared__ float mu_s, rs_s;
    int wave = t >> 6, lane = t & 63;
    if (lane == 0) { sm[wave] = s; ssm[wave] = ss; }
    __syncthreads();
    if (t == 0) {
        float S = 0.f, SS = 0.f;
        for (int w = 0; w < 4; w++) { S += sm[w]; SS += ssm[w]; }
        float mu = S / D_MODEL;
        float var = SS / D_MODEL - mu * mu;
        mu_s = mu;
        rs_s = rsqrtf(var + 1e-5f);
    }
    __syncthreads();
    float mu = mu_s, rs = rs_s;
    float4 gv = ((const float4*)g)[t];
    float4 bv = ((const float4*)b)[t];
    ushort4 o;
    o.x = f2bf((v.x - mu) * rs * gv.x + bv.x);
    o.y = f2bf((v.y - mu) * rs * gv.y + bv.y);
    o.z = f2bf((v.z - mu) * rs * gv.z + bv.z);
    o.w = f2bf((v.w - mu) * rs * gv.w + bv.w);
    *(ushort4*)(h + (size_t)row * D_MODEL + t * 4) = o;
}

// --- transpose + fp32->bf16 for BOTH weights in one launch (K=1024 each) ---
// blockIdx.y < 48: w_qkv [1024][3072]; else: w_out [1024][1024].
__global__ __launch_bounds__(256) void transpose_cvt2(const float* __restrict__ Wa,
                                                      unsigned short* __restrict__ Ta,
                                                      const float* __restrict__ Wb,
                                                      unsigned short* __restrict__ Tb) {
    __shared__ float tile[64][65];
    int by = blockIdx.y;
    const float* W; unsigned short* Wt; int N, n0;
    if (by < 48) { W = Wa; Wt = Ta; N = QKV_COLS; n0 = by * 64; }
    else         { W = Wb; Wt = Tb; N = D_MODEL;  n0 = (by - 48) * 64; }
    const int K = D_MODEL;
    int k0 = blockIdx.x * 64;
    int t = threadIdx.x;
#pragma unroll
    for (int p = 0; p < 16; p++) {
        int idx = p * 256 + t;
        int r = idx >> 6, c = idx & 63;
        tile[r][c] = W[(size_t)(k0 + r) * N + n0 + c];
    }
    __syncthreads();
#pragma unroll
    for (int p = 0; p < 16; p++) {
        int idx = p * 256 + t;
        int r2 = idx >> 6, c2 = idx & 63;
        Wt[(size_t)(n0 + r2) * K + k0 + c2] = f2bf(tile[c2][r2]);
    }
}

// ---- m97-style MFMA bf16 GEMM: C[M,N] = A[M,K] * Bt[N,K]^T, fp32 out ----
__global__ __launch_bounds__(256) void gemm_bt128(const unsigned short* __restrict__ A,
                                                  const unsigned short* __restrict__ Bt,
                                                  float* __restrict__ C,
                                                  int M, int N, int K) {
    __shared__ unsigned short As[128 * 32];
    __shared__ unsigned short Bs[128 * 32];
    int t = threadIdx.x;
    int w = t >> 6, lane = t & 63;
    int l16 = lane & 15, quad = lane >> 4;
    int wr = w >> 1, wc = w & 1;
    int m0 = blockIdx.x * 128, n0 = blockIdx.y * 128;
    int srow = lane >> 2, scol = (lane & 3) * 8;
    int c0 = w * 2, c1 = c0 + 1;

    f32x4 acc[4][4] = {};

    for (int k0 = 0; k0 < K; k0 += 32) {
        __syncthreads();
        load_lds16(A  + (size_t)(m0 + c0 * 16 + srow) * K + k0 + scol, &As[c0 * 512 + lane * 8]);
        load_lds16(A  + (size_t)(m0 + c1 * 16 + srow) * K + k0 + scol, &As[c1 * 512 + lane * 8]);
        load_lds16(Bt + (size_t)(n0 + c0 * 16 + srow) * K + k0 + scol, &Bs[c0 * 512 + lane * 8]);
        load_lds16(Bt + (size_t)(n0 + c1 * 16 + srow) * K + k0 + scol, &Bs[c1 * 512 + lane * 8]);
        __syncthreads();
        bf16x8 a[4], b[4];
#pragma unroll
        for (int mt = 0; mt < 4; mt++)
            a[mt] = *(const bf16x8*)&As[(wr * 64 + mt * 16 + l16) * 32 + quad * 8];
#pragma unroll
        for (int nt = 0; nt < 4; nt++)
            b[nt] = *(const bf16x8*)&Bs[(wc * 64 + nt * 16 + l16) * 32 + quad * 8];
#pragma unroll
        for (int mt = 0; mt < 4; mt++)
#pragma unroll
            for (int nt = 0; nt < 4; nt++)
                acc[mt][nt] = MFMA32(a[mt], b[nt], acc[mt][nt]);
    }
#pragma unroll
    for (int mt = 0; mt < 4; mt++)
#pragma unroll
        for (int nt = 0; nt < 4; nt++)
#pragma unroll
            for (int r = 0; r < 4; r++)
                C[(size_t)(m0 + wr * 64 + mt * 16 + quad * 4 + r) * N + n0 + wc * 64 + nt * 16 + l16] =
                    acc[mt][nt][r];
}

// ---- 64x128-tile variant (for small-N GEMMs needing more blocks/CU) ----
__global__ __launch_bounds__(256) void gemm_bt64(const unsigned short* __restrict__ A,
                                                 const unsigned short* __restrict__ Bt,
                                                 float* __restrict__ C,
                                                 int M, int N, int K) {
    __shared__ unsigned short As[64 * 32];
    __shared__ unsigned short Bs[128 * 32];
    int t = threadIdx.x;
    int w = t >> 6, lane = t & 63;
    int l16 = lane & 15, quad = lane >> 4;
    int wr = w >> 1, wc = w & 1;
    int m0 = blockIdx.x * 64, n0 = blockIdx.y * 128;
    int srow = lane >> 2, scol = (lane & 3) * 8;
    int c0 = w * 2, c1 = c0 + 1;
    int srow2 = t >> 2, scol2 = (t & 3) * 8;

    f32x4 acc[2][4] = {};

    for (int k0 = 0; k0 < K; k0 += 32) {
        __syncthreads();
        load_lds16(A  + (size_t)(m0 + srow2) * K + k0 + scol2, &As[t * 8]);
        load_lds16(Bt + (size_t)(n0 + c0 * 16 + srow) * K + k0 + scol, &Bs[c0 * 512 + lane * 8]);
        load_lds16(Bt + (size_t)(n0 + c1 * 16 + srow) * K + k0 + scol, &Bs[c1 * 512 + lane * 8]);
        __syncthreads();
        bf16x8 a[2], b[4];
#pragma unroll
        for (int mt = 0; mt < 2; mt++)
            a[mt] = *(const bf16x8*)&As[(wr * 32 + mt * 16 + l16) * 32 + quad * 8];
#pragma unroll
        for (int nt = 0; nt < 4; nt++)
            b[nt] = *(const bf16x8*)&Bs[(wc * 64 + nt * 16 + l16) * 32 + quad * 8];
#pragma unroll
        for (int mt = 0; mt < 2; mt++)
#pragma unroll
            for (int nt = 0; nt < 4; nt++)
                acc[mt][nt] = MFMA32(a[mt], b[nt], acc[mt][nt]);
    }
#pragma unroll
    for (int mt = 0; mt < 2; mt++)
#pragma unroll
        for (int nt = 0; nt < 4; nt++)
#pragma unroll
            for (int r = 0; r < 4; r++)
                C[(size_t)(m0 + wr * 32 + mt * 16 + quad * 4 + r) * N + n0 + wc * 64 + nt * 16 + l16] =
                    acc[mt][nt][r];
}

// --------- rope + caches. grid (64 ntiles, 16 heads), 256 thr ----------
// q_bf is PRE-SCALED by 0.125*log2(e) so flash can use exp2f(S) directly.
__global__ __launch_bounds__(256) void rope_cache_kernel(const float* __restrict__ qkv,
                                                         float* __restrict__ out_k,
                                                         float* __restrict__ out_v,
                                                         unsigned short* __restrict__ q_bf,
                                                         unsigned short* __restrict__ k_bf,
                                                         unsigned short* __restrict__ vt_bf) {
    __shared__ unsigned short Vt[64 * 72];
    int nt = blockIdx.x, h = blockIdx.y;
    int n0 = nt * 64;
    int t = threadIdx.x;
    int row = t >> 2;
    int n = n0 + row;
    const float* src = qkv + (size_t)n * QKV_COLS + h * 64;
    size_t nd_base = ((size_t)h * N_SEQ + n) * 64;
    const float QSCALE = 0.18033688011112042f;   // 0.125 * log2(e)
    const float NL2_32 = -0.41524101186092029f;  // -log2(10000)/32
#pragma unroll
    for (int j = 0; j < 4; j++) {
        int c = (t & 3) * 4 + j * 16;
        float4 q4 = *(const float4*)(src + c);
        float4 k4 = *(const float4*)(src + 1024 + c);
        float4 v4 = *(const float4*)(src + 2048 + c);
        *(float4*)(out_k + nd_base + c) = k4;
        *(float4*)(out_v + nd_base + c) = v4;
        float i0 = (float)(c >> 1), i1 = i0 + 1.f;
        float if0 = exp2f(i0 * NL2_32);          // 10000^(-i0/32)
        float if1 = exp2f(i1 * NL2_32);
        float s0, c0s, s1, c1s;
        fast_sincos((float)n * if0, &s0, &c0s);
        fast_sincos((float)n * if1, &s1, &c1s);
        ushort4 qo, ko;
        qo.x = f2bf((q4.x * c0s - q4.y * s0) * QSCALE);
        qo.y = f2bf((q4.y * c0s + q4.x * s0) * QSCALE);
        qo.z = f2bf((q4.z * c1s - q4.w * s1) * QSCALE);
        qo.w = f2bf((q4.w * c1s + q4.z * s1) * QSCALE);
        ko.x = f2bf(k4.x * c0s - k4.y * s0); ko.y = f2bf(k4.y * c0s + k4.x * s0);
        ko.z = f2bf(k4.z * c1s - k4.w * s1); ko.w = f2bf(k4.w * c1s + k4.z * s1);
        *(ushort4*)(q_bf + nd_base + c) = qo;
        *(ushort4*)(k_bf + nd_base + c) = ko;
        ushort4 vo;
        vo.x = f2bf(v4.x); vo.y = f2bf(v4.y); vo.z = f2bf(v4.z); vo.w = f2bf(v4.w);
        *(ushort4*)&Vt[row * 72 + c] = vo;
    }
    __syncthreads();
    int d = t >> 2;
    int nb = (t & 3) * 16;
    unsigned short tmp[16];
#pragma unroll
    for (int i = 0; i < 16; i++) tmp[i] = Vt[(nb + i) * 72 + d];
    unsigned short* dst = vt_bf + ((size_t)h * DHEAD + d) * N_SEQ + n0 + nb;
#pragma unroll
    for (int i = 0; i < 16; i++) dst[i] = tmp[i];
}

// ------------- MFMA flash attention (causal, S^T form, split-K) -------------
// r5 structure + U_TAB static balance. STATIC 1280 blocks; job =
// (h = idx&15, u = U_TAB[idx>>4]). h low bits -> head->XCD L2 affinity
// (FETCH ~12.4 MB). U_TAB -> every CU gets exactly 66 ktiles (was 52..80).
// launch_bounds(256,3): the proven no-spill bound (r4's (256,5) spilled).
// 2-phase double-buffered LDS; l on MFMA pipe; Q pre-scaled -> exp2f direct.
__global__ __launch_bounds__(256, 3) void flash_mfma(const unsigned short* __restrict__ q_bf,
                                                     const unsigned short* __restrict__ k_bf,
                                                     const unsigned short* __restrict__ vt_bf,
                                                     unsigned short* __restrict__ attn_bf,
                                                     float* __restrict__ part_O,
                                                     float* __restrict__ part_l) {
    int idx = blockIdx.x;
    int h = idx & 15;                  // heads in low bits -> spread over XCDs
    int u = U_TAB[idx >> 4];           // balanced slot->job permutation
    int Qt, cc;
    bool partial = (u < 72);
    if (partial) {
        int r = 71 - u;
        if (r < 16)      { Qt = 8 + (r >> 1); cc = r & 1; }
        else if (r < 40) { int q3 = r - 16; int d3 = q3 / 3; Qt = 16 + d3; cc = q3 - 3 * d3; }
        else             { int q4 = r - 40; Qt = 24 + (q4 >> 2); cc = q4 & 3; }
    } else { Qt = 79 - u; cc = 0; }
    int kt0 = cc * 16;
    int kt_end = min(kt0 + 15, 2 * Qt + 1);

    int t = threadIdx.x;
    int w = t >> 6, lane = t & 63;
    int l16 = lane & 15, quad = lane >> 4;
    int sw = l16 & 7;

    __shared__ unsigned short Ks[2][4096];   // 2 x 8KB, double-buffered
    __shared__ unsigned short Vs[2][4096];

    int qr0 = Qt * 128 + w * 32;
    const unsigned short* Kg = k_bf + (size_t)h * N_SEQ * DHEAD;
    const unsigned short* Vg = vt_bf + (size_t)h * DHEAD * N_SEQ;

    bf16x8 bq[2][2];
#pragma unroll
    for (int qg = 0; qg < 2; qg++) {
        const unsigned short* qp = q_bf + ((size_t)h * N_SEQ + qr0 + qg * 16 + l16) * 64 + quad * 8;
        bq[qg][0] = *(const bf16x8*)(qp);
        bq[qg][1] = *(const bf16x8*)(qp + 32);
    }
    f32x4 O[2][4] = {};
    f32x4 Ol[2] = {};                  // row-sum accumulator: l = sum_k P (ones-MFMA)
    int my_kmax = (qr0 + 31) >> 6;

    int srow = t >> 3;
    int scol = ((t & 7) ^ (srow & 7)) * 8;

    // ---- loop-invariant LDS fragment offsets (hoisted; static-indexed) ----
    int koffA[4], koffB[4];
#pragma unroll
    for (int tt = 0; tt < 4; tt++) {
        int krow = tt * 16 + l16;
        koffA[tt] = krow * 64 + ((quad ^ sw) * 8);
        koffB[tt] = krow * 64 + (((quad + 4) ^ sw) * 8);
    }
    int voff[4][4];
#pragma unroll
    for (int tt = 0; tt < 4; tt++)
#pragma unroll
        for (int dt = 0; dt < 4; dt++)
            voff[tt][dt] = (dt * 16 + l16) * 64 +
                           (((2 * tt + (quad >> 1)) ^ sw) * 8) + (quad & 1) * 4;

    // ---- staging pointers (advance by constants each tile) ----
    const unsigned short* kg0 = Kg + (size_t)(kt0 * 64 + srow) * 64 + scol;
    const unsigned short* kg1 = kg0 + 2048;                 // +32 rows
    const unsigned short* vg0 = Vg + (size_t)srow * N_SEQ + kt0 * 64 + scol;
    const unsigned short* vg1 = vg0 + (size_t)32 * N_SEQ;   // +32 d-rows

    const bf16x4 ones4 = {(short)0x3F80, (short)0x3F80, (short)0x3F80, (short)0x3F80};

    // prologue: stage kt0 into buffer 0
    load_lds16(kg0, &Ks[0][t * 8]);
    load_lds16(kg1, &Ks[0][t * 8 + 2048]);
    load_lds16(vg0, &Vs[0][t * 8]);
    load_lds16(vg1, &Vs[0][t * 8 + 2048]);
    kg0 += 4096; kg1 += 4096; vg0 += 64; vg1 += 64;

    // one step: barrier (drains prev stage + prev reads), issue next stage,
    // compute current buffer. Compile-time buffer bases fold into offsets.
    auto step = [&](int kt, const unsigned short* KC, const unsigned short* VC,
                    unsigned short* KN, unsigned short* VN) {
        __syncthreads();
        if (kt < kt_end) {
            load_lds16(kg0, KN + t * 8);
            load_lds16(kg1, KN + t * 8 + 2048);
            load_lds16(vg0, VN + t * 8);
            load_lds16(vg1, VN + t * 8 + 2048);
            kg0 += 4096; kg1 += 4096; vg0 += 64; vg1 += 64;
        }
        if (kt > my_kmax) return;
        int k0 = kt << 6;

        bf16x4 pf[2][4];
#pragma unroll
        for (int tt = 0; tt < 4; tt++) {
            int kbase = k0 + tt * 16;
            bf16x4 pz = (bf16x4){0, 0, 0, 0};
            if (kbase >= qr0 + 32) { pf[0][tt] = pz; pf[1][tt] = pz; continue; }
            bf16x8 kf0 = *(const bf16x8*)&KC[koffA[tt]];
            bf16x8 kf1 = *(const bf16x8*)&KC[koffB[tt]];
#pragma unroll
            for (int qg = 0; qg < 2; qg++) {
                int qb = qr0 + qg * 16;
                if (kbase > qb) { pf[qg][tt] = pz; continue; }
                f32x4 s = (f32x4){0.f, 0.f, 0.f, 0.f};
                s = MFMA32(kf0, bq[qg][0], s);
                s = MFMA32(kf1, bq[qg][1], s);
                float p0 = exp2f(s[0]);     // Q pre-scaled by 0.125*log2(e)
                float p1 = exp2f(s[1]);
                float p2 = exp2f(s[2]);
                float p3 = exp2f(s[3]);
                if (kbase == qb) {   // diagonal tile: mask key > q
                    if (quad * 4 + 0 > l16) p0 = 0.f;
                    if (quad * 4 + 1 > l16) p1 = 0.f;
                    if (quad * 4 + 2 > l16) p2 = 0.f;
                    if (quad * 4 + 3 > l16) p3 = 0.f;
                }
                pf[qg][tt] = pack_bf16x4(p0, p1, p2, p3);
                // l on the MFMA pipe (A=ones => all C rows = row-sum)
                Ol[qg] = MFMA16(ones4, pf[qg][tt], Ol[qg]);
            }
        }
        // O^T += V^T * P^T, 16-key chunks, P from registers
        __builtin_amdgcn_s_setprio(1);
#pragma unroll
        for (int tt = 0; tt < 4; tt++) {
            if (k0 + tt * 16 < qr0 + 32) {
#pragma unroll
                for (int dt = 0; dt < 4; dt++) {
                    bf16x4 va = *(const bf16x4*)&VC[voff[tt][dt]];
                    O[0][dt] = MFMA16(va, pf[0][tt], O[0][dt]);
                    O[1][dt] = MFMA16(va, pf[1][tt], O[1][dt]);
                }
            }
        }
        __builtin_amdgcn_s_setprio(0);
    };

    for (int kt = kt0; kt <= kt_end; ) {
        step(kt, Ks[0], Vs[0], Ks[1], Vs[1]); kt++;
        if (kt > kt_end) break;
        step(kt, Ks[1], Vs[1], Ks[0], Vs[0]); kt++;
    }

#pragma unroll
    for (int qg = 0; qg < 2; qg++) {
        float l = Ol[qg][0];
        if (!partial) {
            float inv = 1.0f / l;
#pragma unroll
            for (int dt = 0; dt < 4; dt++) {
                ushort4 o;
                o.x = f2bf(O[qg][dt][0] * inv);
                o.y = f2bf(O[qg][dt][1] * inv);
                o.z = f2bf(O[qg][dt][2] * inv);
                o.w = f2bf(O[qg][dt][3] * inv);
                *(ushort4*)(attn_bf + (size_t)(qr0 + qg * 16 + l16) * D_MODEL + h * 64 + dt * 16 + quad * 4) = o;
            }
        } else {
            int uid = h * 72 + u;
            size_t ob = (size_t)uid * 8192;
            int qcol = w * 32 + qg * 16 + l16;
#pragma unroll
            for (int dt = 0; dt < 4; dt++)
#pragma unroll
                for (int r = 0; r < 4; r++)
                    part_O[ob + (size_t)(dt * 16 + quad * 4 + r) * 128 + qcol] = O[qg][dt][r];
            if (quad == 0) part_l[uid * 128 + qcol] = l;
        }
    }
}

// ------------- combine partials: sum chunks, normalize, -> attn_bf -------------
// grid (24,16,2): z splits the 64 d-dims into 2 halves -> 768 blocks (3/CU).
__global__ __launch_bounds__(256) void combine_kernel(const float* __restrict__ part_O,
                                                      const float* __restrict__ part_l,
                                                      unsigned short* __restrict__ attn_bf) {
    int Qt = 8 + blockIdx.x;       // 8..31
    int h  = blockIdx.y;
    int nc = (Qt + 8) >> 3;        // 2,3,4 chunks
    int t = threadIdx.x;
    int q = t & 127;
    int dh = blockIdx.z * 32 + (t >> 7) * 16;
    float l = 0.f;
    float acc[16];
#pragma unroll
    for (int d = 0; d < 16; d++) acc[d] = 0.f;
    for (int c = 0; c < nc; c++) {
        int r;
        if (Qt < 16)      r = 2 * (Qt - 8) + c;
        else if (Qt < 24) r = 16 + 3 * (Qt - 16) + c;
        else              r = 40 + 4 * (Qt - 24) + c;
        int uid = h * 72 + (71 - r);
        l += part_l[uid * 128 + q];
        const float* po = part_O + (size_t)uid * 8192 + (size_t)dh * 128 + q;
#pragma unroll
        for (int d = 0; d < 16; d++) acc[d] += po[d * 128];
    }
    float inv = 1.0f / l;
    unsigned short* op = attn_bf + (size_t)(Qt * 128 + q) * D_MODEL + h * 64 + dh;
#pragma unroll
    for (int d = 0; d < 16; d++) op[d] = f2bf(acc[d] * inv);
}

extern "C" void kernel_launch(void* const* d_in, const int* in_sizes, int n_in,
                              void* d_out, int out_size, void* d_ws, size_t ws_size,
                              hipStream_t stream) {
    const float* x     = (const float*)d_in[0];
    const float* w_qkv = (const float*)d_in[1];
    const float* w_out = (const float*)d_in[2];
    const float* ln_g  = (const float*)d_in[3];
    const float* ln_b  = (const float*)d_in[4];

    float* out   = (float*)d_out;                       // [4096,1024]
    float* out_k = (float*)d_out + 4194304;             // [16,4096,64]
    float* out_v = (float*)d_out + 8388608;             // [16,4096,64]

    char* ws = (char*)d_ws;
    const size_t MiB = 1048576;
    float*          qkv_f   = (float*)(ws);                    // [4096,3072] fp32   @0..48 (dead after rope)
    unsigned short* h_bf    = (unsigned short*)(ws + 48*MiB);  // bf16 @48..56 (dead after gemm1)
    unsigned short* wqkvT   = (unsigned short*)(ws + 56*MiB);  // bf16 @56..62 (dead after gemm1)
    unsigned short* q_bf    = (unsigned short*)(ws + 48*MiB);  // [16,4096,64] bf16  @48..56
    unsigned short* k_bf    = (unsigned short*)(ws + 56*MiB);  // [16,4096,64] bf16  @56..64
    unsigned short* vt_bf   = (unsigned short*)(ws + 64*MiB);  // [16,64,4096] bf16  @64..72
    unsigned short* attn_bf = (unsigned short*)(ws);           // [4096,1024] bf16   @0..8
    float*          part_l  = (float*)(ws + 8*MiB);            // [1152][128] fp32   @8..8.56
    float*          part_O  = (float*)(ws + 9*MiB);            // [1152][64][128]    @9..46.7
    unsigned short* woutT   = (unsigned short*)(ws + 72*MiB);  // [1024,1024] bf16   @72..74

    transpose_cvt2<<<dim3(16, 64), 256, 0, stream>>>(w_qkv, wqkvT, w_out, woutT);
    ln_kernel<<<N_SEQ, 256, 0, stream>>>(x, ln_g, ln_b, h_bf);
    gemm_bt128<<<dim3(32, 24), 256, 0, stream>>>(h_bf, wqkvT, qkv_f, N_SEQ, QKV_COLS, D_MODEL);
    rope_cache_kernel<<<dim3(64, 16), 256, 0, stream>>>(qkv_f, out_k, out_v, q_bf, k_bf, vt_bf);
    flash_mfma<<<1280, 256, 0, stream>>>(q_bf, k_bf, vt_bf, attn_bf, part_O, part_l);
    combine_kernel<<<dim3(24, 16, 2), 256, 0, stream>>>(part_O, part_l, attn_bf);
    gemm_bt64<<<dim3(64, 8), 256, 0, stream>>>(attn_bf, woutT, out, N_SEQ, D_MODEL, D_MODEL);
}